// Round 1
// baseline (1082.224 us; speedup 1.0000x reference)
//
#include <hip/hip_runtime.h>

#define N_VAR   100000
#define N_CSTR  50000
#define NEDGE   1000000
#define DIM     64

// Coarse buckets: 128 destination nodes each.
#define NBK_N 782           // ceil(100000/128)
#define NBK_C 391           // ceil(50000/128)
#define NBK_T 1173
#define NCHUNK 245          // ceil(1e6/4096) pass-A chunks per side

// ---------------------------------------------------------------------------
// Workspace layout (4-byte units):
//   0:         stats      256 (float)  -- zeroed
//   256:       bhist     1280 (int)    -- zeroed
//   1536:      ab         256 (float)
//   1792:      gbase_n    800 (int)
//   2592:      gbase_c    416 (int)
//   3008:      gcur_n     800 (int)
//   3808:      gcur_c     416 (int)
//   4224..     (off arrays retired -- fused kernel needs no CSR)
//   154232:    xcb     1600000 (bf16 normalized cstr feats, 50000x64)
//   1754232:   xnb     3200000 (bf16 normalized var  feats, 100000x64)
//   4954232:   ent_n   2000000 (int2)
//   6954232:   ent_c   2000000 (int2)
// ---------------------------------------------------------------------------
#define OFF_STATS  0
#define OFF_BHIST  256
#define OFF_AB     1536
#define OFF_GBN    1792
#define OFF_GBC    2592
#define OFF_GCN    3008
#define OFF_GCC    3808
#define OFF_XCB    154232
#define OFF_XNB    1754232
#define OFF_ENT_N  4954232
#define OFF_ENT_C  6954232
#define WS_ZERO_N  1536

typedef __attribute__((ext_vector_type(8))) short bf16x8;
typedef __attribute__((ext_vector_type(4))) float f32x4;

// ---------------------------------------------------------------------------
// BN column stats.
// ---------------------------------------------------------------------------
__global__ __launch_bounds__(256) void bn_stats_k(const float* __restrict__ x, int n,
                                                  float* __restrict__ stats) {
  int c = threadIdx.x & 63;
  int rg = threadIdx.x >> 6;
  float s = 0.f, q = 0.f;
  for (int r = blockIdx.x * 4 + rg; r < n; r += gridDim.x * 4) {
    float v = x[r * DIM + c];
    s += v;
    q += v * v;
  }
  __shared__ float sb[256], qb[256];
  sb[threadIdx.x] = s;
  qb[threadIdx.x] = q;
  __syncthreads();
  if (rg == 0) {
    s = sb[c] + sb[c + 64] + sb[c + 128] + sb[c + 192];
    q = qb[c] + qb[c + 64] + qb[c + 128] + qb[c + 192];
    atomicAdd(&stats[c], s);
    atomicAdd(&stats[64 + c], q);
  }
}

__global__ void bn_finalize_k(const float* __restrict__ stats,
                              const float* __restrict__ gn, const float* __restrict__ bn,
                              const float* __restrict__ gc, const float* __restrict__ bc,
                              float* __restrict__ ab) {
  int t = threadIdx.x;  // 0..127
  int c = t & 63;
  bool isC = t >= 64;
  const float* st = stats + (isC ? 128 : 0);
  float n = isC ? (float)N_CSTR : (float)N_VAR;
  float mean = st[c] / n;
  float var = st[64 + c] / n - mean * mean;
  float g = isC ? gc[c] : gn[c];
  float be = isC ? bc[c] : bn[c];
  float a = g * rsqrtf(var + 1e-5f);
  float b = be - mean * a;
  float* o = ab + (isC ? 128 : 0);
  o[c] = a;
  o[64 + c] = b;
}

// ---------------------------------------------------------------------------
// bf16 round-to-nearest-even + normalized table build.
// ---------------------------------------------------------------------------
__device__ __forceinline__ unsigned short f2bf(float f) {
  unsigned u = __float_as_uint(f);
  return (unsigned short)((u + 0x7FFFu + ((u >> 16) & 1u)) >> 16);
}

__global__ __launch_bounds__(256) void cvt_k(const float4* __restrict__ src4,
                                             const float* __restrict__ ab,
                                             ushort4* __restrict__ dst, int n4) {
  int i4 = blockIdx.x * 256 + threadIdx.x;
  if (i4 >= n4) return;
  float4 v = src4[i4];
  int c0 = (i4 << 2) & 63;
  ushort4 o;
  o.x = f2bf(fmaf(v.x, ab[c0 + 0], ab[64 + c0 + 0]));
  o.y = f2bf(fmaf(v.y, ab[c0 + 1], ab[64 + c0 + 1]));
  o.z = f2bf(fmaf(v.z, ab[c0 + 2], ab[64 + c0 + 2]));
  o.w = f2bf(fmaf(v.w, ab[c0 + 3], ab[64 + c0 + 3]));
  dst[i4] = o;
}

// ---------------------------------------------------------------------------
// Coarse bucket histogram (both sides), LDS-aggregated.
// ---------------------------------------------------------------------------
__global__ __launch_bounds__(256) void bhist_k(const int4* __restrict__ es4,
                                               const int4* __restrict__ ed4,
                                               int* __restrict__ ws) {
  __shared__ int h[1280];
  for (int i = threadIdx.x; i < 1280; i += 256) h[i] = 0;
  __syncthreads();
  int stride = gridDim.x * 256;
  for (int i4 = blockIdx.x * 256 + threadIdx.x; i4 < NEDGE / 4; i4 += stride) {
    int4 d = ed4[i4];
    int4 s = es4[i4];
    atomicAdd(&h[d.x >> 7], 1);
    atomicAdd(&h[d.y >> 7], 1);
    atomicAdd(&h[d.z >> 7], 1);
    atomicAdd(&h[d.w >> 7], 1);
    atomicAdd(&h[NBK_N + (s.x >> 7)], 1);
    atomicAdd(&h[NBK_N + (s.y >> 7)], 1);
    atomicAdd(&h[NBK_N + (s.z >> 7)], 1);
    atomicAdd(&h[NBK_N + (s.w >> 7)], 1);
  }
  __syncthreads();
  int* gh = ws + OFF_BHIST;
  for (int i = threadIdx.x; i < NBK_T; i += 256)
    if (h[i]) atomicAdd(&gh[i], h[i]);
}

// ---------------------------------------------------------------------------
// Scan bucket counts -> gbase (+sentinel) and gcur. One WG.
// ---------------------------------------------------------------------------
__global__ __launch_bounds__(256) void bscan_k(int* __restrict__ ws) {
  __shared__ int sb[256];
  int t = threadIdx.x;
#pragma unroll
  for (int seg = 0; seg < 2; ++seg) {
    int nbk = seg ? NBK_C : NBK_N;
    const int* h = ws + OFF_BHIST + (seg ? NBK_N : 0);
    int* gb = ws + (seg ? OFF_GBC : OFF_GBN);
    int* gc = ws + (seg ? OFF_GCC : OFF_GCN);
    int base = t * 4;
    int c[4];
    int s0 = 0;
#pragma unroll
    for (int j = 0; j < 4; ++j) {
      c[j] = (base + j < nbk) ? h[base + j] : 0;
      s0 += c[j];
    }
    sb[t] = s0;
    __syncthreads();
    for (int d = 1; d < 256; d <<= 1) {
      int v = (t >= d) ? sb[t - d] : 0;
      __syncthreads();
      sb[t] += v;
      __syncthreads();
    }
    int ex = sb[t] - s0;
#pragma unroll
    for (int j = 0; j < 4; ++j) {
      if (base + j < nbk) {
        gb[base + j] = ex;
        gc[base + j] = ex;
      }
      ex += c[j];
    }
    if (t == 255) gb[nbk] = sb[255];  // sentinel = NEDGE
    __syncthreads();
  }
}

// ---------------------------------------------------------------------------
// Pass A: LDS multi-split of 4096-edge chunks into coarse buckets.
// Payload: low 17 bits = src index, bits 17..23 = dst local row (0..127).
// ---------------------------------------------------------------------------
__global__ __launch_bounds__(256) void passA_k(const int4* __restrict__ es4,
                                               const int4* __restrict__ ed4,
                                               const float4* __restrict__ ea4,
                                               int* __restrict__ ws) {
  __shared__ int cntL[1024];
  __shared__ int runoffL[1024];
  __shared__ int gblL[1024];
  __shared__ int2 dataL[4096];
  __shared__ unsigned short bidL[4096];
  __shared__ int sbL[256];
  int side = (blockIdx.x >= NCHUNK);
  int chunk = side ? blockIdx.x - NCHUNK : blockIdx.x;
  int nbk = side ? NBK_C : NBK_N;
  int* gcur = ws + (side ? OFF_GCC : OFF_GCN);
  int2* ent = (int2*)(ws + (side ? OFF_ENT_C : OFF_ENT_N));
  int t = threadIdx.x;
  for (int i = t; i < 1024; i += 256) cntL[i] = 0;
  __syncthreads();
  int e0 = chunk * 4096;
  int base4 = chunk * 1024 + t * 4;
  int pk[16];
  int2 pay[16];
#pragma unroll
  for (int j = 0; j < 4; ++j) {
    int i4 = base4 + j;
    if (i4 < NEDGE / 4) {
      int4 sv = es4[i4];
      int4 dv = ed4[i4];
      float4 wv = ea4[i4];
      int ss[4] = {sv.x, sv.y, sv.z, sv.w};
      int dd[4] = {dv.x, dv.y, dv.z, dv.w};
      float ww[4] = {wv.x, wv.y, wv.z, wv.w};
#pragma unroll
      for (int k = 0; k < 4; ++k) {
        int s = ss[k], d = dd[k];
        int b = side ? (s >> 7) : (d >> 7);
        int pl = side ? (d | ((s & 127) << 17)) : (s | ((d & 127) << 17));
        int rank = atomicAdd(&cntL[b], 1);
        pk[j * 4 + k] = b * 4096 + rank;
        pay[j * 4 + k] = make_int2(pl, __float_as_int(ww[k]));
      }
    } else {
#pragma unroll
      for (int k = 0; k < 4; ++k) pk[j * 4 + k] = -1;
    }
  }
  __syncthreads();
  int base = t * 4;
  int c[4];
  int s0 = 0;
#pragma unroll
  for (int j = 0; j < 4; ++j) {
    c[j] = cntL[base + j];
    s0 += c[j];
  }
  sbL[t] = s0;
  __syncthreads();
  for (int d = 1; d < 256; d <<= 1) {
    int v = (t >= d) ? sbL[t - d] : 0;
    __syncthreads();
    sbL[t] += v;
    __syncthreads();
  }
  int ex = sbL[t] - s0;
#pragma unroll
  for (int j = 0; j < 4; ++j) {
    runoffL[base + j] = ex;
    ex += c[j];
  }
  __syncthreads();
  for (int b = t; b < nbk; b += 256) {
    int cc = cntL[b];
    gblL[b] = cc ? atomicAdd(&gcur[b], cc) : 0;
  }
  __syncthreads();
#pragma unroll
  for (int j = 0; j < 16; ++j) {
    if (pk[j] >= 0) {
      int b = pk[j] >> 12;
      int slot = runoffL[b] + (pk[j] & 4095);
      dataL[slot] = pay[j];
      bidL[slot] = (unsigned short)b;
    }
  }
  __syncthreads();
  int chunkN = min(4096, NEDGE - e0);
  for (int i = t; i < chunkN; i += 256) {
    int b = bidL[i];
    ent[gblL[b] + (i - runoffL[b])] = dataL[i];
  }
}

// ---------------------------------------------------------------------------
// Fused aggregate + MFMA epilogue, one coarse bucket (128 rows) per block.
//   Phase 1: scatter-accumulate bucket edges into LDS agg[128][64] (pad 65)
//            via ds_add_f32; per-row edge counts in LDS.
//   Phase 2: out[r][c] = relu([agg/cnt | xv] (K=128) . [w_rel ; w_root]
//            + b_rel[c] + xv[r][c]) with mfma_f32_16x16x32_bf16, 8 row-tiles,
//            wave wv handles tiles wv, wv+4. xv recomputed from raw in f32.
// LDS pad +1 float: ds_add lanes (lr+lane)%32 -> 2/bank free; A-frag reads
// (65*l16 + 8*quad + j) -> residues l16+8q hit each bank exactly 2x -> free.
// ---------------------------------------------------------------------------
__global__ __launch_bounds__(256) void fused_k(
    const unsigned short* __restrict__ tab, const int2* __restrict__ ent,
    const int* __restrict__ gbase, const float* __restrict__ raw,
    const float* __restrict__ ab, const float* __restrict__ w_rel,
    const float* __restrict__ b_rel, const float* __restrict__ w_root,
    float* __restrict__ out, int n) {
  __shared__ float aggL[128 * 65];
  __shared__ int cntL[128];
  __shared__ float rcpL[128];
  int bx = blockIdx.x;
  int t = threadIdx.x, lane = t & 63, wv = t >> 6;
  int quad = lane >> 4, l16 = lane & 15;

  for (int i = t; i < 128 * 65; i += 256) aggL[i] = 0.f;
  if (t < 128) cntL[t] = 0;

  // B fragments: bfrag[nt][kc] = W128[n=nt*16+l16][k=kc*32+quad*8+j],
  // W128[c] = concat(w_rel[c][:], w_root[c][:]).
  bf16x8 bfrag[4][4];
#pragma unroll
  for (int nt = 0; nt < 4; ++nt) {
    int c = nt * 16 + l16;
#pragma unroll
    for (int kc = 0; kc < 4; ++kc) {
      int bk = kc * 32 + quad * 8;
      const float* wsrc = (bk < 64) ? (w_rel + c * 64 + bk) : (w_root + c * 64 + bk - 64);
      bf16x8 f;
#pragma unroll
      for (int j = 0; j < 8; ++j) f[j] = (short)f2bf(wsrc[j]);
      bfrag[nt][kc] = f;
    }
  }
  float av0[8], bv0[8], av1[8], bv1[8];
#pragma unroll
  for (int j = 0; j < 8; ++j) {
    av0[j] = ab[quad * 8 + j];
    bv0[j] = ab[64 + quad * 8 + j];
    av1[j] = ab[32 + quad * 8 + j];
    bv1[j] = ab[96 + quad * 8 + j];
  }
  __syncthreads();

  // ---- Phase 1: edge scatter into LDS ----
  int beg = gbase[bx], end = gbase[bx + 1];
  int e0;
  for (e0 = beg + wv * 8; e0 + 8 <= end; e0 += 32) {
    int2 p[8];
#pragma unroll
    for (int j = 0; j < 8; ++j) p[j] = ent[e0 + j];
    float v[8];
#pragma unroll
    for (int j = 0; j < 8; ++j)
      v[j] = __uint_as_float((unsigned)tab[(p[j].x & 0x1FFFF) * DIM + lane] << 16);
#pragma unroll
    for (int j = 0; j < 8; ++j) {
      int lr = (p[j].x >> 17) & 127;
      atomicAdd(&aggL[lr * 65 + lane], v[j] * __int_as_float(p[j].y));
      if (lane == 0) atomicAdd(&cntL[lr], 1);
    }
  }
  for (int e = e0; e < end; ++e) {
    int2 p = ent[e];
    float v = __uint_as_float((unsigned)tab[(p.x & 0x1FFFF) * DIM + lane] << 16);
    int lr = (p.x >> 17) & 127;
    atomicAdd(&aggL[lr * 65 + lane], v * __int_as_float(p.y));
    if (lane == 0) atomicAdd(&cntL[lr], 1);
  }
  __syncthreads();
  if (t < 128) rcpL[t] = 1.f / fmaxf((float)cntL[t], 1.f);
  __syncthreads();

  // ---- Phase 2: MFMA epilogue ----
  for (int tl = wv; tl < 8; tl += 4) {
    int r0 = bx * 128 + tl * 16;
    if (r0 >= n) continue;  // n % 16 == 0: tiles with r0 < n are full
    const float* aggr = aggL + (tl * 16 + l16) * 65;
    float rc = rcpL[tl * 16 + l16];
    const float* rawr = raw + (long)(r0 + l16) * DIM;
    bf16x8 a0, a1, a2, a3;
#pragma unroll
    for (int j = 0; j < 8; ++j) {
      a0[j] = (short)f2bf(aggr[quad * 8 + j] * rc);
      a1[j] = (short)f2bf(aggr[32 + quad * 8 + j] * rc);
      a2[j] = (short)f2bf(fmaf(rawr[quad * 8 + j], av0[j], bv0[j]));
      a3[j] = (short)f2bf(fmaf(rawr[32 + quad * 8 + j], av1[j], bv1[j]));
    }
    f32x4 acc[4];
#pragma unroll
    for (int nt = 0; nt < 4; ++nt) {
      acc[nt] = (f32x4){0.f, 0.f, 0.f, 0.f};
      acc[nt] = __builtin_amdgcn_mfma_f32_16x16x32_bf16(a0, bfrag[nt][0], acc[nt], 0, 0, 0);
      acc[nt] = __builtin_amdgcn_mfma_f32_16x16x32_bf16(a1, bfrag[nt][1], acc[nt], 0, 0, 0);
      acc[nt] = __builtin_amdgcn_mfma_f32_16x16x32_bf16(a2, bfrag[nt][2], acc[nt], 0, 0, 0);
      acc[nt] = __builtin_amdgcn_mfma_f32_16x16x32_bf16(a3, bfrag[nt][3], acc[nt], 0, 0, 0);
    }
#pragma unroll
    for (int nt = 0; nt < 4; ++nt) {
      int c = nt * 16 + l16;
      float aC = ab[c], bC = ab[64 + c], brC = b_rel[c];
#pragma unroll
      for (int reg = 0; reg < 4; ++reg) {
        int r = r0 + quad * 4 + reg;
        float xv = fmaf(raw[(long)r * DIM + c], aC, bC);
        out[(long)r * DIM + c] = fmaxf(acc[nt][reg] + brC + xv, 0.f);
      }
    }
  }
}

extern "C" void kernel_launch(void* const* d_in, const int* in_sizes, int n_in,
                              void* d_out, int out_size, void* d_ws, size_t ws_size,
                              hipStream_t stream) {
  const float* vf = (const float*)d_in[0];
  const float* cf = (const float*)d_in[1];
  const int* es = (const int*)d_in[2];
  const int* ed = (const int*)d_in[3];
  const float* ea = (const float*)d_in[4];
  const float* gn = (const float*)d_in[5];
  const float* bn = (const float*)d_in[6];
  const float* gc = (const float*)d_in[7];
  const float* bc = (const float*)d_in[8];
  const float* n_rel_w = (const float*)d_in[9];
  const float* n_rel_b = (const float*)d_in[10];
  const float* n_root_w = (const float*)d_in[11];
  const float* c_rel_w = (const float*)d_in[12];
  const float* c_rel_b = (const float*)d_in[13];
  const float* c_root_w = (const float*)d_in[14];
  float* out = (float*)d_out;
  int* wsi = (int*)d_ws;
  float* wsf = (float*)d_ws;

  float* stats = wsf + OFF_STATS;
  float* ab = wsf + OFF_AB;
  ushort4* xcb = (ushort4*)(wsi + OFF_XCB);
  ushort4* xnb = (ushort4*)(wsi + OFF_XNB);
  const unsigned short* xcb_s = (const unsigned short*)(wsi + OFF_XCB);
  const unsigned short* xnb_s = (const unsigned short*)(wsi + OFF_XNB);
  const int2* ent_n = (const int2*)(wsi + OFF_ENT_N);
  const int2* ent_c = (const int2*)(wsi + OFF_ENT_C);

  hipMemsetAsync(d_ws, 0, (size_t)WS_ZERO_N * sizeof(int), stream);

  bn_stats_k<<<512, 256, 0, stream>>>(vf, N_VAR, stats);
  bn_stats_k<<<512, 256, 0, stream>>>(cf, N_CSTR, stats + 128);
  bn_finalize_k<<<1, 128, 0, stream>>>(stats, gn, bn, gc, bc, ab);

  cvt_k<<<(N_CSTR * DIM / 4 + 255) / 256, 256, 0, stream>>>((const float4*)cf, ab + 128,
                                                            xcb, N_CSTR * DIM / 4);
  cvt_k<<<(N_VAR * DIM / 4 + 255) / 256, 256, 0, stream>>>((const float4*)vf, ab,
                                                           xnb, N_VAR * DIM / 4);

  bhist_k<<<128, 256, 0, stream>>>((const int4*)es, (const int4*)ed, wsi);
  bscan_k<<<1, 256, 0, stream>>>(wsi);
  passA_k<<<2 * NCHUNK, 256, 0, stream>>>((const int4*)es, (const int4*)ed,
                                          (const float4*)ea, wsi);

  fused_k<<<NBK_N, 256, 0, stream>>>(xcb_s, ent_n, wsi + OFF_GBN, vf, ab,
                                     n_rel_w, n_rel_b, n_root_w, out, N_VAR);
  fused_k<<<NBK_C, 256, 0, stream>>>(xnb_s, ent_c, wsi + OFF_GBC, cf, ab + 128,
                                     c_rel_w, c_rel_b, c_root_w,
                                     out + (long)N_VAR * DIM, N_CSTR);
}

// Round 2
// 403.041 us; speedup vs baseline: 2.6851x; 2.6851x over previous
//
#include <hip/hip_runtime.h>

#define N_VAR   100000
#define N_CSTR  50000
#define NEDGE   1000000
#define DIM     64

// Coarse buckets: 128 destination nodes each.
#define NBK_N 782           // ceil(100000/128)
#define NBK_C 391           // ceil(50000/128)
#define NBK_T 1173
#define NCHUNK 245          // ceil(1e6/4096) pass-A chunks per side

// ---------------------------------------------------------------------------
// Workspace layout (4-byte units), ~35.8 MB total:
//   0:         stats      256 (float)  -- zeroed
//   256:       bhist     1280 (int)    -- zeroed
//   1536:      ab         256 (float)
//   1792:      gbase_n    800 (int)
//   2592:      gbase_c    416 (int)
//   3008:      gcur_n     800 (int)
//   3808:      gcur_c     416 (int)
//   4224:      off_node 100004 (int)
//   104228:    off_cstr  50004 (int)
//   154232:    xcb     1600000 (bf16 normalized cstr feats, 50000x64)
//   1754232:   xnb     3200000 (bf16 normalized var  feats, 100000x64)
//   4954232:   ent_n   2000000 (int2)
//   6954232:   ent_c   2000000 (int2)
// ---------------------------------------------------------------------------
#define OFF_STATS  0
#define OFF_BHIST  256
#define OFF_AB     1536
#define OFF_GBN    1792
#define OFF_GBC    2592
#define OFF_GCN    3008
#define OFF_GCC    3808
#define OFF_OFF_N  4224
#define OFF_OFF_C  104228
#define OFF_XCB    154232
#define OFF_XNB    1754232
#define OFF_ENT_N  4954232
#define OFF_ENT_C  6954232
#define WS_ZERO_N  1536

typedef __attribute__((ext_vector_type(8))) short bf16x8;
typedef __attribute__((ext_vector_type(4))) float f32x4;

// ---------------------------------------------------------------------------
// BN column stats.
// ---------------------------------------------------------------------------
__global__ __launch_bounds__(256) void bn_stats_k(const float* __restrict__ x, int n,
                                                  float* __restrict__ stats) {
  int c = threadIdx.x & 63;
  int rg = threadIdx.x >> 6;
  float s = 0.f, q = 0.f;
  for (int r = blockIdx.x * 4 + rg; r < n; r += gridDim.x * 4) {
    float v = x[r * DIM + c];
    s += v;
    q += v * v;
  }
  __shared__ float sb[256], qb[256];
  sb[threadIdx.x] = s;
  qb[threadIdx.x] = q;
  __syncthreads();
  if (rg == 0) {
    s = sb[c] + sb[c + 64] + sb[c + 128] + sb[c + 192];
    q = qb[c] + qb[c + 64] + qb[c + 128] + qb[c + 192];
    atomicAdd(&stats[c], s);
    atomicAdd(&stats[64 + c], q);
  }
}

__global__ void bn_finalize_k(const float* __restrict__ stats,
                              const float* __restrict__ gn, const float* __restrict__ bn,
                              const float* __restrict__ gc, const float* __restrict__ bc,
                              float* __restrict__ ab) {
  int t = threadIdx.x;  // 0..127
  int c = t & 63;
  bool isC = t >= 64;
  const float* st = stats + (isC ? 128 : 0);
  float n = isC ? (float)N_CSTR : (float)N_VAR;
  float mean = st[c] / n;
  float var = st[64 + c] / n - mean * mean;
  float g = isC ? gc[c] : gn[c];
  float be = isC ? bc[c] : bn[c];
  float a = g * rsqrtf(var + 1e-5f);
  float b = be - mean * a;
  float* o = ab + (isC ? 128 : 0);
  o[c] = a;
  o[64 + c] = b;
}

// ---------------------------------------------------------------------------
// bf16 round-to-nearest-even + normalized table build.
// ---------------------------------------------------------------------------
__device__ __forceinline__ unsigned short f2bf(float f) {
  unsigned u = __float_as_uint(f);
  return (unsigned short)((u + 0x7FFFu + ((u >> 16) & 1u)) >> 16);
}

__global__ __launch_bounds__(256) void cvt_k(const float4* __restrict__ src4,
                                             const float* __restrict__ ab,
                                             ushort4* __restrict__ dst, int n4) {
  int i4 = blockIdx.x * 256 + threadIdx.x;
  if (i4 >= n4) return;
  float4 v = src4[i4];
  int c0 = (i4 << 2) & 63;
  ushort4 o;
  o.x = f2bf(fmaf(v.x, ab[c0 + 0], ab[64 + c0 + 0]));
  o.y = f2bf(fmaf(v.y, ab[c0 + 1], ab[64 + c0 + 1]));
  o.z = f2bf(fmaf(v.z, ab[c0 + 2], ab[64 + c0 + 2]));
  o.w = f2bf(fmaf(v.w, ab[c0 + 3], ab[64 + c0 + 3]));
  dst[i4] = o;
}

// ---------------------------------------------------------------------------
// Coarse bucket histogram (both sides), LDS-aggregated.
// ---------------------------------------------------------------------------
__global__ __launch_bounds__(256) void bhist_k(const int4* __restrict__ es4,
                                               const int4* __restrict__ ed4,
                                               int* __restrict__ ws) {
  __shared__ int h[1280];
  for (int i = threadIdx.x; i < 1280; i += 256) h[i] = 0;
  __syncthreads();
  int stride = gridDim.x * 256;
  for (int i4 = blockIdx.x * 256 + threadIdx.x; i4 < NEDGE / 4; i4 += stride) {
    int4 d = ed4[i4];
    int4 s = es4[i4];
    atomicAdd(&h[d.x >> 7], 1);
    atomicAdd(&h[d.y >> 7], 1);
    atomicAdd(&h[d.z >> 7], 1);
    atomicAdd(&h[d.w >> 7], 1);
    atomicAdd(&h[NBK_N + (s.x >> 7)], 1);
    atomicAdd(&h[NBK_N + (s.y >> 7)], 1);
    atomicAdd(&h[NBK_N + (s.z >> 7)], 1);
    atomicAdd(&h[NBK_N + (s.w >> 7)], 1);
  }
  __syncthreads();
  int* gh = ws + OFF_BHIST;
  for (int i = threadIdx.x; i < NBK_T; i += 256)
    if (h[i]) atomicAdd(&gh[i], h[i]);
}

// ---------------------------------------------------------------------------
// Scan bucket counts -> gbase (+sentinel) and gcur; seed off sentinels. One WG.
// ---------------------------------------------------------------------------
__global__ __launch_bounds__(256) void bscan_k(int* __restrict__ ws) {
  __shared__ int sb[256];
  int t = threadIdx.x;
#pragma unroll
  for (int seg = 0; seg < 2; ++seg) {
    int nbk = seg ? NBK_C : NBK_N;
    const int* h = ws + OFF_BHIST + (seg ? NBK_N : 0);
    int* gb = ws + (seg ? OFF_GBC : OFF_GBN);
    int* gc = ws + (seg ? OFF_GCC : OFF_GCN);
    int base = t * 4;
    int c[4];
    int s0 = 0;
#pragma unroll
    for (int j = 0; j < 4; ++j) {
      c[j] = (base + j < nbk) ? h[base + j] : 0;
      s0 += c[j];
    }
    sb[t] = s0;
    __syncthreads();
    for (int d = 1; d < 256; d <<= 1) {
      int v = (t >= d) ? sb[t - d] : 0;
      __syncthreads();
      sb[t] += v;
      __syncthreads();
    }
    int ex = sb[t] - s0;
#pragma unroll
    for (int j = 0; j < 4; ++j) {
      if (base + j < nbk) {
        gb[base + j] = ex;
        gc[base + j] = ex;
      }
      ex += c[j];
    }
    if (t == 255) gb[nbk] = sb[255];  // sentinel = NEDGE
    __syncthreads();
  }
  if (t == 0) {
    ws[OFF_OFF_N + N_VAR] = NEDGE;
    ws[OFF_OFF_C + N_CSTR] = NEDGE;
  }
}

// ---------------------------------------------------------------------------
// Pass A: LDS multi-split of 4096-edge chunks into coarse buckets.
// ---------------------------------------------------------------------------
__global__ __launch_bounds__(256) void passA_k(const int4* __restrict__ es4,
                                               const int4* __restrict__ ed4,
                                               const float4* __restrict__ ea4,
                                               int* __restrict__ ws) {
  __shared__ int cntL[1024];
  __shared__ int runoffL[1024];
  __shared__ int gblL[1024];
  __shared__ int2 dataL[4096];
  __shared__ unsigned short bidL[4096];
  __shared__ int sbL[256];
  int side = (blockIdx.x >= NCHUNK);
  int chunk = side ? blockIdx.x - NCHUNK : blockIdx.x;
  int nbk = side ? NBK_C : NBK_N;
  int* gcur = ws + (side ? OFF_GCC : OFF_GCN);
  int2* ent = (int2*)(ws + (side ? OFF_ENT_C : OFF_ENT_N));
  int t = threadIdx.x;
  for (int i = t; i < 1024; i += 256) cntL[i] = 0;
  __syncthreads();
  int e0 = chunk * 4096;
  int base4 = chunk * 1024 + t * 4;
  int pk[16];
  int2 pay[16];
#pragma unroll
  for (int j = 0; j < 4; ++j) {
    int i4 = base4 + j;
    if (i4 < NEDGE / 4) {
      int4 sv = es4[i4];
      int4 dv = ed4[i4];
      float4 wv = ea4[i4];
      int ss[4] = {sv.x, sv.y, sv.z, sv.w};
      int dd[4] = {dv.x, dv.y, dv.z, dv.w};
      float ww[4] = {wv.x, wv.y, wv.z, wv.w};
#pragma unroll
      for (int k = 0; k < 4; ++k) {
        int s = ss[k], d = dd[k];
        int b = side ? (s >> 7) : (d >> 7);
        int pl = side ? (d | ((s & 127) << 17)) : (s | ((d & 127) << 17));
        int rank = atomicAdd(&cntL[b], 1);
        pk[j * 4 + k] = b * 4096 + rank;
        pay[j * 4 + k] = make_int2(pl, __float_as_int(ww[k]));
      }
    } else {
#pragma unroll
      for (int k = 0; k < 4; ++k) pk[j * 4 + k] = -1;
    }
  }
  __syncthreads();
  int base = t * 4;
  int c[4];
  int s0 = 0;
#pragma unroll
  for (int j = 0; j < 4; ++j) {
    c[j] = cntL[base + j];
    s0 += c[j];
  }
  sbL[t] = s0;
  __syncthreads();
  for (int d = 1; d < 256; d <<= 1) {
    int v = (t >= d) ? sbL[t - d] : 0;
    __syncthreads();
    sbL[t] += v;
    __syncthreads();
  }
  int ex = sbL[t] - s0;
#pragma unroll
  for (int j = 0; j < 4; ++j) {
    runoffL[base + j] = ex;
    ex += c[j];
  }
  __syncthreads();
  for (int b = t; b < nbk; b += 256) {
    int cc = cntL[b];
    gblL[b] = cc ? atomicAdd(&gcur[b], cc) : 0;
  }
  __syncthreads();
#pragma unroll
  for (int j = 0; j < 16; ++j) {
    if (pk[j] >= 0) {
      int b = pk[j] >> 12;
      int slot = runoffL[b] + (pk[j] & 4095);
      dataL[slot] = pay[j];
      bidL[slot] = (unsigned short)b;
    }
  }
  __syncthreads();
  int chunkN = min(4096, NEDGE - e0);
  for (int i = t; i < chunkN; i += 256) {
    int b = bidL[i];
    ent[gblL[b] + (i - runoffL[b])] = dataL[i];
  }
}

// ---------------------------------------------------------------------------
// Per-bucket in-LDS counting sort -> fully sorted CSR, in place.
// ---------------------------------------------------------------------------
__global__ __launch_bounds__(256) void sort_k(int* __restrict__ ws) {
  __shared__ int2 data[4096];
  __shared__ int hcnt[128], hrank[128];
  __shared__ int sb[128];
  int x = blockIdx.x;
  int side = (x >= NBK_N);
  int bk = side ? x - NBK_N : x;
  const int* gbase = ws + (side ? OFF_GBC : OFF_GBN);
  int2* ent = (int2*)(ws + (side ? OFF_ENT_C : OFF_ENT_N));
  int* off = ws + (side ? OFF_OFF_C : OFF_OFF_N);
  int n = side ? N_CSTR : N_VAR;
  int t = threadIdx.x;
  int beg = gbase[bk], end = gbase[bk + 1];
  int cnt = end - beg;
  if (t < 128) hcnt[t] = 0;
  __syncthreads();
  for (int i = t; i < cnt; i += 256) {
    int2 e = ent[beg + i];
    data[i] = e;
    atomicAdd(&hcnt[(e.x >> 17) & 127], 1);
  }
  __syncthreads();
  if (t < 128) sb[t] = hcnt[t];
  __syncthreads();
  for (int d = 1; d < 128; d <<= 1) {
    int v = 0;
    if (t < 128 && t >= d) v = sb[t - d];
    __syncthreads();
    if (t < 128) sb[t] += v;
    __syncthreads();
  }
  if (t < 128) {
    int ex = sb[t] - hcnt[t];
    hrank[t] = ex;
    int r = bk * 128 + t;
    if (r < n) off[r] = beg + ex;
  }
  __syncthreads();
  for (int i = t; i < cnt; i += 256) {
    int2 e = data[i];
    int dl = (e.x >> 17) & 127;
    int pos = atomicAdd(&hrank[dl], 1);
    ent[beg + pos] = make_int2(e.x & 0x1FFFF, e.y);
  }
}

// ---------------------------------------------------------------------------
// Fused gather + MFMA epilogue. One block = 16 consecutive sorted rows.
//   Phase 1 (proven gather_k pattern): wave wv accumulates rows r0+wv*4..+3 in
//   registers (lane = column, unroll-8 over edges), writes mean row to a tiny
//   16x65 LDS tile (pad 65: write (lr+lane)%32 and A-frag read residues both
//   2/bank -> conflict-free).
//   Phase 2: wave wv computes column tile nt=wv of
//     out[r][c] = relu([agg | xv](K=128) . [w_rel ; w_root] + b_rel[c] + xv)
//   with 4x mfma_f32_16x16x32_bf16. A: row=l16, k=quad*8+j; D: col=l16,
//   row=quad*4+reg (HW-verified). Residual xv recomputed in f32.
// agg never touches HBM (saves ~77 MB round trip + 2 dispatches vs split).
// ---------------------------------------------------------------------------
__global__ __launch_bounds__(256) void gmf_k(
    const unsigned short* __restrict__ tab, const int2* __restrict__ ent,
    const int* __restrict__ off, const float* __restrict__ raw,
    const float* __restrict__ ab, const float* __restrict__ w_rel,
    const float* __restrict__ b_rel, const float* __restrict__ w_root,
    float* __restrict__ out, int n) {
  __shared__ float aggS[16 * 65];
  int t = threadIdx.x, lane = t & 63, wv = t >> 6;
  int quad = lane >> 4, l16 = lane & 15;
  int r0 = blockIdx.x << 4;  // n % 16 == 0, grid = n/16: all tiles full

  // B fragment for this wave's column tile (nt = wv):
  // bfrag[kc] = W128[n=wv*16+l16][k=kc*32+quad*8+j],
  // W128[c] = concat(w_rel[c][:], w_root[c][:]).  L1/L2-hot after first blocks.
  int c = (wv << 4) + l16;
  bf16x8 bfrag[4];
#pragma unroll
  for (int kc = 0; kc < 4; ++kc) {
    int bk = kc * 32 + quad * 8;
    const float* wsrc = (bk < 64) ? (w_rel + c * 64 + bk) : (w_root + c * 64 + bk - 64);
    bf16x8 f;
#pragma unroll
    for (int j = 0; j < 8; ++j) f[j] = (short)f2bf(wsrc[j]);
    bfrag[kc] = f;
  }
  float av0[8], bv0[8], av1[8], bv1[8];
#pragma unroll
  for (int j = 0; j < 8; ++j) {
    av0[j] = ab[quad * 8 + j];
    bv0[j] = ab[64 + quad * 8 + j];
    av1[j] = ab[32 + quad * 8 + j];
    bv1[j] = ab[96 + quad * 8 + j];
  }

  // ---- Phase 1: register gather, 4 rows per wave ----
#define BF(hv) __uint_as_float(((unsigned)(hv)) << 16)
  for (int rr = 0; rr < 4; ++rr) {
    int lr = (wv << 2) + rr;
    int r = r0 + lr;
    int beg = off[r], end = off[r + 1];
    float acc0 = 0.f, acc1 = 0.f;
    int e = beg;
    if (e < end && (e & 1)) {
      int2 p = ent[e];
      acc0 = fmaf(BF(tab[p.x * DIM + lane]), __int_as_float(p.y), acc0);
      ++e;
    }
    for (; e + 8 <= end; e += 8) {
      int4 p0 = *reinterpret_cast<const int4*>(&ent[e]);
      int4 p1 = *reinterpret_cast<const int4*>(&ent[e + 2]);
      int4 p2 = *reinterpret_cast<const int4*>(&ent[e + 4]);
      int4 p3 = *reinterpret_cast<const int4*>(&ent[e + 6]);
      float v0 = BF(tab[p0.x * DIM + lane]);
      float v1 = BF(tab[p0.z * DIM + lane]);
      float v2 = BF(tab[p1.x * DIM + lane]);
      float v3 = BF(tab[p1.z * DIM + lane]);
      float v4 = BF(tab[p2.x * DIM + lane]);
      float v5 = BF(tab[p2.z * DIM + lane]);
      float v6 = BF(tab[p3.x * DIM + lane]);
      float v7 = BF(tab[p3.z * DIM + lane]);
      acc0 = fmaf(v0, __int_as_float(p0.y), acc0);
      acc1 = fmaf(v1, __int_as_float(p0.w), acc1);
      acc0 = fmaf(v2, __int_as_float(p1.y), acc0);
      acc1 = fmaf(v3, __int_as_float(p1.w), acc1);
      acc0 = fmaf(v4, __int_as_float(p2.y), acc0);
      acc1 = fmaf(v5, __int_as_float(p2.w), acc1);
      acc0 = fmaf(v6, __int_as_float(p3.y), acc0);
      acc1 = fmaf(v7, __int_as_float(p3.w), acc1);
    }
    for (; e + 2 <= end; e += 2) {
      int4 p = *reinterpret_cast<const int4*>(&ent[e]);
      acc0 = fmaf(BF(tab[p.x * DIM + lane]), __int_as_float(p.y), acc0);
      acc1 = fmaf(BF(tab[p.z * DIM + lane]), __int_as_float(p.w), acc1);
    }
    if (e < end) {
      int2 p = ent[e];
      acc0 = fmaf(BF(tab[p.x * DIM + lane]), __int_as_float(p.y), acc0);
    }
    aggS[lr * 65 + lane] = (acc0 + acc1) / fmaxf((float)(end - beg), 1.f);
  }
#undef BF
  __syncthreads();

  // ---- Phase 2: MFMA epilogue, wave wv -> column tile nt = wv ----
  const float* aggr = aggS + l16 * 65;
  const float* rawr = raw + (long)(r0 + l16) * DIM;
  bf16x8 a0, a1, a2, a3;
#pragma unroll
  for (int j = 0; j < 8; ++j) {
    a0[j] = (short)f2bf(aggr[quad * 8 + j]);
    a1[j] = (short)f2bf(aggr[32 + quad * 8 + j]);
    a2[j] = (short)f2bf(fmaf(rawr[quad * 8 + j], av0[j], bv0[j]));
    a3[j] = (short)f2bf(fmaf(rawr[32 + quad * 8 + j], av1[j], bv1[j]));
  }
  f32x4 acc = (f32x4){0.f, 0.f, 0.f, 0.f};
  acc = __builtin_amdgcn_mfma_f32_16x16x32_bf16(a0, bfrag[0], acc, 0, 0, 0);
  acc = __builtin_amdgcn_mfma_f32_16x16x32_bf16(a1, bfrag[1], acc, 0, 0, 0);
  acc = __builtin_amdgcn_mfma_f32_16x16x32_bf16(a2, bfrag[2], acc, 0, 0, 0);
  acc = __builtin_amdgcn_mfma_f32_16x16x32_bf16(a3, bfrag[3], acc, 0, 0, 0);
  float aC = ab[c], bC = ab[64 + c], brC = b_rel[c];
#pragma unroll
  for (int reg = 0; reg < 4; ++reg) {
    int r = r0 + quad * 4 + reg;
    float xv = fmaf(raw[(long)r * DIM + c], aC, bC);
    out[(long)r * DIM + c] = fmaxf(acc[reg] + brC + xv, 0.f);
  }
}

extern "C" void kernel_launch(void* const* d_in, const int* in_sizes, int n_in,
                              void* d_out, int out_size, void* d_ws, size_t ws_size,
                              hipStream_t stream) {
  const float* vf = (const float*)d_in[0];
  const float* cf = (const float*)d_in[1];
  const int* es = (const int*)d_in[2];
  const int* ed = (const int*)d_in[3];
  const float* ea = (const float*)d_in[4];
  const float* gn = (const float*)d_in[5];
  const float* bn = (const float*)d_in[6];
  const float* gc = (const float*)d_in[7];
  const float* bc = (const float*)d_in[8];
  const float* n_rel_w = (const float*)d_in[9];
  const float* n_rel_b = (const float*)d_in[10];
  const float* n_root_w = (const float*)d_in[11];
  const float* c_rel_w = (const float*)d_in[12];
  const float* c_rel_b = (const float*)d_in[13];
  const float* c_root_w = (const float*)d_in[14];
  float* out = (float*)d_out;
  int* wsi = (int*)d_ws;
  float* wsf = (float*)d_ws;

  float* stats = wsf + OFF_STATS;
  float* ab = wsf + OFF_AB;
  ushort4* xcb = (ushort4*)(wsi + OFF_XCB);
  ushort4* xnb = (ushort4*)(wsi + OFF_XNB);
  const unsigned short* xcb_s = (const unsigned short*)(wsi + OFF_XCB);
  const unsigned short* xnb_s = (const unsigned short*)(wsi + OFF_XNB);
  const int2* ent_n = (const int2*)(wsi + OFF_ENT_N);
  const int2* ent_c = (const int2*)(wsi + OFF_ENT_C);

  hipMemsetAsync(d_ws, 0, (size_t)WS_ZERO_N * sizeof(int), stream);

  bn_stats_k<<<512, 256, 0, stream>>>(vf, N_VAR, stats);
  bn_stats_k<<<512, 256, 0, stream>>>(cf, N_CSTR, stats + 128);
  bn_finalize_k<<<1, 128, 0, stream>>>(stats, gn, bn, gc, bc, ab);

  cvt_k<<<(N_CSTR * DIM / 4 + 255) / 256, 256, 0, stream>>>((const float4*)cf, ab + 128,
                                                            xcb, N_CSTR * DIM / 4);
  cvt_k<<<(N_VAR * DIM / 4 + 255) / 256, 256, 0, stream>>>((const float4*)vf, ab,
                                                           xnb, N_VAR * DIM / 4);

  bhist_k<<<128, 256, 0, stream>>>((const int4*)es, (const int4*)ed, wsi);
  bscan_k<<<1, 256, 0, stream>>>(wsi);
  passA_k<<<2 * NCHUNK, 256, 0, stream>>>((const int4*)es, (const int4*)ed,
                                          (const float4*)ea, wsi);
  sort_k<<<NBK_T, 256, 0, stream>>>(wsi);

  gmf_k<<<N_VAR / 16, 256, 0, stream>>>(xcb_s, ent_n, wsi + OFF_OFF_N, vf, ab,
                                        n_rel_w, n_rel_b, n_root_w, out, N_VAR);
  gmf_k<<<N_CSTR / 16, 256, 0, stream>>>(xnb_s, ent_c, wsi + OFF_OFF_C, cf, ab + 128,
                                         c_rel_w, c_rel_b, c_root_w,
                                         out + (long)N_VAR * DIM, N_CSTR);
}

// Round 3
// 358.740 us; speedup vs baseline: 3.0167x; 1.1235x over previous
//
#include <hip/hip_runtime.h>

#define N_VAR   100000
#define N_CSTR  50000
#define NEDGE   1000000
#define DIM     64

// Coarse buckets: 128 destination nodes each.
#define NBK_N 782           // ceil(100000/128)
#define NBK_C 391           // ceil(50000/128)
#define NBK_T 1173
#define NCHUNK 245          // ceil(1e6/4096) pass-A chunks per side

// ---------------------------------------------------------------------------
// Workspace layout (4-byte units), ~35.8 MB total:
//   0:         stats      256 (float)  -- zeroed
//   256:       bhist     1280 (int)    -- zeroed
//   1536:      ab         256 (float)
//   1792:      gbase_n    800 (int)
//   2592:      gbase_c    416 (int)
//   3008:      gcur_n     800 (int)
//   3808:      gcur_c     416 (int)
//   4224:      off_node 100004 (int)
//   104228:    off_cstr  50004 (int)
//   154232:    xcb     1600000 (bf16 normalized cstr feats, 50000x64)
//   1754232:   xnb     3200000 (bf16 normalized var  feats, 100000x64)
//   4954232:   ent_n   2000000 (int2)
//   6954232:   ent_c   2000000 (int2)
// ---------------------------------------------------------------------------
#define OFF_STATS  0
#define OFF_BHIST  256
#define OFF_AB     1536
#define OFF_GBN    1792
#define OFF_GBC    2592
#define OFF_GCN    3008
#define OFF_GCC    3808
#define OFF_OFF_N  4224
#define OFF_OFF_C  104228
#define OFF_XCB    154232
#define OFF_XNB    1754232
#define OFF_ENT_N  4954232
#define OFF_ENT_C  6954232
#define WS_ZERO_N  1536

typedef __attribute__((ext_vector_type(8))) short bf16x8;
typedef __attribute__((ext_vector_type(4))) float f32x4;

// ---------------------------------------------------------------------------
// BN column stats.
// ---------------------------------------------------------------------------
__global__ __launch_bounds__(256) void bn_stats_k(const float* __restrict__ x, int n,
                                                  float* __restrict__ stats) {
  int c = threadIdx.x & 63;
  int rg = threadIdx.x >> 6;
  float s = 0.f, q = 0.f;
  for (int r = blockIdx.x * 4 + rg; r < n; r += gridDim.x * 4) {
    float v = x[r * DIM + c];
    s += v;
    q += v * v;
  }
  __shared__ float sb[256], qb[256];
  sb[threadIdx.x] = s;
  qb[threadIdx.x] = q;
  __syncthreads();
  if (rg == 0) {
    s = sb[c] + sb[c + 64] + sb[c + 128] + sb[c + 192];
    q = qb[c] + qb[c + 64] + qb[c + 128] + qb[c + 192];
    atomicAdd(&stats[c], s);
    atomicAdd(&stats[64 + c], q);
  }
}

__global__ void bn_finalize_k(const float* __restrict__ stats,
                              const float* __restrict__ gn, const float* __restrict__ bn,
                              const float* __restrict__ gc, const float* __restrict__ bc,
                              float* __restrict__ ab) {
  int t = threadIdx.x;  // 0..127
  int c = t & 63;
  bool isC = t >= 64;
  const float* st = stats + (isC ? 128 : 0);
  float n = isC ? (float)N_CSTR : (float)N_VAR;
  float mean = st[c] / n;
  float var = st[64 + c] / n - mean * mean;
  float g = isC ? gc[c] : gn[c];
  float be = isC ? bc[c] : bn[c];
  float a = g * rsqrtf(var + 1e-5f);
  float b = be - mean * a;
  float* o = ab + (isC ? 128 : 0);
  o[c] = a;
  o[64 + c] = b;
}

// ---------------------------------------------------------------------------
// bf16 round-to-nearest-even + normalized table build.
// ---------------------------------------------------------------------------
__device__ __forceinline__ unsigned short f2bf(float f) {
  unsigned u = __float_as_uint(f);
  return (unsigned short)((u + 0x7FFFu + ((u >> 16) & 1u)) >> 16);
}

__global__ __launch_bounds__(256) void cvt_k(const float4* __restrict__ src4,
                                             const float* __restrict__ ab,
                                             ushort4* __restrict__ dst, int n4) {
  int i4 = blockIdx.x * 256 + threadIdx.x;
  if (i4 >= n4) return;
  float4 v = src4[i4];
  int c0 = (i4 << 2) & 63;
  ushort4 o;
  o.x = f2bf(fmaf(v.x, ab[c0 + 0], ab[64 + c0 + 0]));
  o.y = f2bf(fmaf(v.y, ab[c0 + 1], ab[64 + c0 + 1]));
  o.z = f2bf(fmaf(v.z, ab[c0 + 2], ab[64 + c0 + 2]));
  o.w = f2bf(fmaf(v.w, ab[c0 + 3], ab[64 + c0 + 3]));
  dst[i4] = o;
}

// ---------------------------------------------------------------------------
// Coarse bucket histogram (both sides), LDS-aggregated.
// ---------------------------------------------------------------------------
__global__ __launch_bounds__(256) void bhist_k(const int4* __restrict__ es4,
                                               const int4* __restrict__ ed4,
                                               int* __restrict__ ws) {
  __shared__ int h[1280];
  for (int i = threadIdx.x; i < 1280; i += 256) h[i] = 0;
  __syncthreads();
  int stride = gridDim.x * 256;
  for (int i4 = blockIdx.x * 256 + threadIdx.x; i4 < NEDGE / 4; i4 += stride) {
    int4 d = ed4[i4];
    int4 s = es4[i4];
    atomicAdd(&h[d.x >> 7], 1);
    atomicAdd(&h[d.y >> 7], 1);
    atomicAdd(&h[d.z >> 7], 1);
    atomicAdd(&h[d.w >> 7], 1);
    atomicAdd(&h[NBK_N + (s.x >> 7)], 1);
    atomicAdd(&h[NBK_N + (s.y >> 7)], 1);
    atomicAdd(&h[NBK_N + (s.z >> 7)], 1);
    atomicAdd(&h[NBK_N + (s.w >> 7)], 1);
  }
  __syncthreads();
  int* gh = ws + OFF_BHIST;
  for (int i = threadIdx.x; i < NBK_T; i += 256)
    if (h[i]) atomicAdd(&gh[i], h[i]);
}

// ---------------------------------------------------------------------------
// Scan bucket counts -> gbase (+sentinel) and gcur; seed off sentinels. One WG.
// ---------------------------------------------------------------------------
__global__ __launch_bounds__(256) void bscan_k(int* __restrict__ ws) {
  __shared__ int sb[256];
  int t = threadIdx.x;
#pragma unroll
  for (int seg = 0; seg < 2; ++seg) {
    int nbk = seg ? NBK_C : NBK_N;
    const int* h = ws + OFF_BHIST + (seg ? NBK_N : 0);
    int* gb = ws + (seg ? OFF_GBC : OFF_GBN);
    int* gc = ws + (seg ? OFF_GCC : OFF_GCN);
    int base = t * 4;
    int c[4];
    int s0 = 0;
#pragma unroll
    for (int j = 0; j < 4; ++j) {
      c[j] = (base + j < nbk) ? h[base + j] : 0;
      s0 += c[j];
    }
    sb[t] = s0;
    __syncthreads();
    for (int d = 1; d < 256; d <<= 1) {
      int v = (t >= d) ? sb[t - d] : 0;
      __syncthreads();
      sb[t] += v;
      __syncthreads();
    }
    int ex = sb[t] - s0;
#pragma unroll
    for (int j = 0; j < 4; ++j) {
      if (base + j < nbk) {
        gb[base + j] = ex;
        gc[base + j] = ex;
      }
      ex += c[j];
    }
    if (t == 255) gb[nbk] = sb[255];  // sentinel = NEDGE
    __syncthreads();
  }
  if (t == 0) {
    ws[OFF_OFF_N + N_VAR] = NEDGE;
    ws[OFF_OFF_C + N_CSTR] = NEDGE;
  }
}

// ---------------------------------------------------------------------------
// Pass A: LDS multi-split of 4096-edge chunks into coarse buckets.
// ---------------------------------------------------------------------------
__global__ __launch_bounds__(256) void passA_k(const int4* __restrict__ es4,
                                               const int4* __restrict__ ed4,
                                               const float4* __restrict__ ea4,
                                               int* __restrict__ ws) {
  __shared__ int cntL[1024];
  __shared__ int runoffL[1024];
  __shared__ int gblL[1024];
  __shared__ int2 dataL[4096];
  __shared__ unsigned short bidL[4096];
  __shared__ int sbL[256];
  int side = (blockIdx.x >= NCHUNK);
  int chunk = side ? blockIdx.x - NCHUNK : blockIdx.x;
  int nbk = side ? NBK_C : NBK_N;
  int* gcur = ws + (side ? OFF_GCC : OFF_GCN);
  int2* ent = (int2*)(ws + (side ? OFF_ENT_C : OFF_ENT_N));
  int t = threadIdx.x;
  for (int i = t; i < 1024; i += 256) cntL[i] = 0;
  __syncthreads();
  int e0 = chunk * 4096;
  int base4 = chunk * 1024 + t * 4;
  int pk[16];
  int2 pay[16];
#pragma unroll
  for (int j = 0; j < 4; ++j) {
    int i4 = base4 + j;
    if (i4 < NEDGE / 4) {
      int4 sv = es4[i4];
      int4 dv = ed4[i4];
      float4 wv = ea4[i4];
      int ss[4] = {sv.x, sv.y, sv.z, sv.w};
      int dd[4] = {dv.x, dv.y, dv.z, dv.w};
      float ww[4] = {wv.x, wv.y, wv.z, wv.w};
#pragma unroll
      for (int k = 0; k < 4; ++k) {
        int s = ss[k], d = dd[k];
        int b = side ? (s >> 7) : (d >> 7);
        int pl = side ? (d | ((s & 127) << 17)) : (s | ((d & 127) << 17));
        int rank = atomicAdd(&cntL[b], 1);
        pk[j * 4 + k] = b * 4096 + rank;
        pay[j * 4 + k] = make_int2(pl, __float_as_int(ww[k]));
      }
    } else {
#pragma unroll
      for (int k = 0; k < 4; ++k) pk[j * 4 + k] = -1;
    }
  }
  __syncthreads();
  int base = t * 4;
  int c[4];
  int s0 = 0;
#pragma unroll
  for (int j = 0; j < 4; ++j) {
    c[j] = cntL[base + j];
    s0 += c[j];
  }
  sbL[t] = s0;
  __syncthreads();
  for (int d = 1; d < 256; d <<= 1) {
    int v = (t >= d) ? sbL[t - d] : 0;
    __syncthreads();
    sbL[t] += v;
    __syncthreads();
  }
  int ex = sbL[t] - s0;
#pragma unroll
  for (int j = 0; j < 4; ++j) {
    runoffL[base + j] = ex;
    ex += c[j];
  }
  __syncthreads();
  for (int b = t; b < nbk; b += 256) {
    int cc = cntL[b];
    gblL[b] = cc ? atomicAdd(&gcur[b], cc) : 0;
  }
  __syncthreads();
#pragma unroll
  for (int j = 0; j < 16; ++j) {
    if (pk[j] >= 0) {
      int b = pk[j] >> 12;
      int slot = runoffL[b] + (pk[j] & 4095);
      dataL[slot] = pay[j];
      bidL[slot] = (unsigned short)b;
    }
  }
  __syncthreads();
  int chunkN = min(4096, NEDGE - e0);
  for (int i = t; i < chunkN; i += 256) {
    int b = bidL[i];
    ent[gblL[b] + (i - runoffL[b])] = dataL[i];
  }
}

// ---------------------------------------------------------------------------
// Per-bucket in-LDS counting sort -> fully sorted CSR, in place.
// ---------------------------------------------------------------------------
__global__ __launch_bounds__(256) void sort_k(int* __restrict__ ws) {
  __shared__ int2 data[4096];
  __shared__ int hcnt[128], hrank[128];
  __shared__ int sb[128];
  int x = blockIdx.x;
  int side = (x >= NBK_N);
  int bk = side ? x - NBK_N : x;
  const int* gbase = ws + (side ? OFF_GBC : OFF_GBN);
  int2* ent = (int2*)(ws + (side ? OFF_ENT_C : OFF_ENT_N));
  int* off = ws + (side ? OFF_OFF_C : OFF_OFF_N);
  int n = side ? N_CSTR : N_VAR;
  int t = threadIdx.x;
  int beg = gbase[bk], end = gbase[bk + 1];
  int cnt = end - beg;
  if (t < 128) hcnt[t] = 0;
  __syncthreads();
  for (int i = t; i < cnt; i += 256) {
    int2 e = ent[beg + i];
    data[i] = e;
    atomicAdd(&hcnt[(e.x >> 17) & 127], 1);
  }
  __syncthreads();
  if (t < 128) sb[t] = hcnt[t];
  __syncthreads();
  for (int d = 1; d < 128; d <<= 1) {
    int v = 0;
    if (t < 128 && t >= d) v = sb[t - d];
    __syncthreads();
    if (t < 128) sb[t] += v;
    __syncthreads();
  }
  if (t < 128) {
    int ex = sb[t] - hcnt[t];
    hrank[t] = ex;
    int r = bk * 128 + t;
    if (r < n) off[r] = beg + ex;
  }
  __syncthreads();
  for (int i = t; i < cnt; i += 256) {
    int2 e = data[i];
    int dl = (e.x >> 17) & 127;
    int pos = atomicAdd(&hrank[dl], 1);
    ent[beg + pos] = make_int2(e.x & 0x1FFFF, e.y);
  }
}

// ---------------------------------------------------------------------------
// Fused gather + MFMA epilogue. One block = 1024 threads = 16 waves = 16 rows;
// ONE ROW PER WAVE (restores round-0 gather TLP: 100K/50K independent waves).
//   Phase 1: wave wv gathers row r0+wv in registers (lane = column, unroll-8,
//   scalarized ent addresses), writes mean row to 16x65 LDS tile (pad 65:
//   write banks (wv+lane)%32 = 2/bank, A-frag reads 2/bank -> conflict-free).
//   Phase 2: after one barrier, waves 0..3 compute column tiles nt=wv of
//     out[r][c] = relu([agg | xv](K=128) . [w_rel ; w_root] + b_rel[c] + xv)
//   with 4x mfma_f32_16x16x32_bf16; waves 4..15 retire. A: row=l16,
//   k=quad*8+j; D: col=l16, row=quad*4+reg (HW-verified). xv in f32.
// agg never touches HBM (saves ~77 MB round trip + 2 dispatches vs split).
// ---------------------------------------------------------------------------
__global__ __launch_bounds__(1024) void gmf_k(
    const unsigned short* __restrict__ tab, const int2* __restrict__ ent,
    const int* __restrict__ off, const float* __restrict__ raw,
    const float* __restrict__ ab, const float* __restrict__ w_rel,
    const float* __restrict__ b_rel, const float* __restrict__ w_root,
    float* __restrict__ out, int n) {
  __shared__ float aggS[16 * 65];
  int t = threadIdx.x, lane = t & 63;
  int wv = __builtin_amdgcn_readfirstlane(t >> 6);
  int r0 = blockIdx.x << 4;  // n % 16 == 0, grid = n/16: all tiles full

  // ---- Phase 1: register gather, one row per wave ----
  {
    int r = r0 + wv;
    int beg = __builtin_amdgcn_readfirstlane(off[r]);
    int end = __builtin_amdgcn_readfirstlane(off[r + 1]);
    float acc0 = 0.f, acc1 = 0.f;
    int e = beg;
#define BF(hv) __uint_as_float(((unsigned)(hv)) << 16)
    if (e < end && (e & 1)) {
      int2 p = ent[e];
      acc0 = fmaf(BF(tab[p.x * DIM + lane]), __int_as_float(p.y), acc0);
      ++e;
    }
    for (; e + 8 <= end; e += 8) {
      int4 p0 = *reinterpret_cast<const int4*>(&ent[e]);
      int4 p1 = *reinterpret_cast<const int4*>(&ent[e + 2]);
      int4 p2 = *reinterpret_cast<const int4*>(&ent[e + 4]);
      int4 p3 = *reinterpret_cast<const int4*>(&ent[e + 6]);
      float v0 = BF(tab[p0.x * DIM + lane]);
      float v1 = BF(tab[p0.z * DIM + lane]);
      float v2 = BF(tab[p1.x * DIM + lane]);
      float v3 = BF(tab[p1.z * DIM + lane]);
      float v4 = BF(tab[p2.x * DIM + lane]);
      float v5 = BF(tab[p2.z * DIM + lane]);
      float v6 = BF(tab[p3.x * DIM + lane]);
      float v7 = BF(tab[p3.z * DIM + lane]);
      acc0 = fmaf(v0, __int_as_float(p0.y), acc0);
      acc1 = fmaf(v1, __int_as_float(p0.w), acc1);
      acc0 = fmaf(v2, __int_as_float(p1.y), acc0);
      acc1 = fmaf(v3, __int_as_float(p1.w), acc1);
      acc0 = fmaf(v4, __int_as_float(p2.y), acc0);
      acc1 = fmaf(v5, __int_as_float(p2.w), acc1);
      acc0 = fmaf(v6, __int_as_float(p3.y), acc0);
      acc1 = fmaf(v7, __int_as_float(p3.w), acc1);
    }
    for (; e + 2 <= end; e += 2) {
      int4 p = *reinterpret_cast<const int4*>(&ent[e]);
      acc0 = fmaf(BF(tab[p.x * DIM + lane]), __int_as_float(p.y), acc0);
      acc1 = fmaf(BF(tab[p.z * DIM + lane]), __int_as_float(p.w), acc1);
    }
    if (e < end) {
      int2 p = ent[e];
      acc0 = fmaf(BF(tab[p.x * DIM + lane]), __int_as_float(p.y), acc0);
    }
#undef BF
    aggS[wv * 65 + lane] = (acc0 + acc1) / fmaxf((float)(end - beg), 1.f);
  }
  __syncthreads();
  if (wv >= 4) return;

  // ---- Phase 2: MFMA epilogue, wave wv -> column tile nt = wv ----
  int quad = lane >> 4, l16 = lane & 15;
  int c = (wv << 4) + l16;
  // bfrag[kc] = W128[n=c][k=kc*32+quad*8+j], W128[c]=concat(w_rel[c],w_root[c])
  bf16x8 bfrag[4];
#pragma unroll
  for (int kc = 0; kc < 4; ++kc) {
    int bk = kc * 32 + quad * 8;
    const float* wsrc = (bk < 64) ? (w_rel + c * 64 + bk) : (w_root + c * 64 + bk - 64);
    bf16x8 f;
#pragma unroll
    for (int j = 0; j < 8; ++j) f[j] = (short)f2bf(wsrc[j]);
    bfrag[kc] = f;
  }
  float av0[8], bv0[8], av1[8], bv1[8];
#pragma unroll
  for (int j = 0; j < 8; ++j) {
    av0[j] = ab[quad * 8 + j];
    bv0[j] = ab[64 + quad * 8 + j];
    av1[j] = ab[32 + quad * 8 + j];
    bv1[j] = ab[96 + quad * 8 + j];
  }
  const float* aggr = aggS + l16 * 65;
  const float* rawr = raw + (long)(r0 + l16) * DIM;
  bf16x8 a0, a1, a2, a3;
#pragma unroll
  for (int j = 0; j < 8; ++j) {
    a0[j] = (short)f2bf(aggr[quad * 8 + j]);
    a1[j] = (short)f2bf(aggr[32 + quad * 8 + j]);
    a2[j] = (short)f2bf(fmaf(rawr[quad * 8 + j], av0[j], bv0[j]));
    a3[j] = (short)f2bf(fmaf(rawr[32 + quad * 8 + j], av1[j], bv1[j]));
  }
  f32x4 acc = (f32x4){0.f, 0.f, 0.f, 0.f};
  acc = __builtin_amdgcn_mfma_f32_16x16x32_bf16(a0, bfrag[0], acc, 0, 0, 0);
  acc = __builtin_amdgcn_mfma_f32_16x16x32_bf16(a1, bfrag[1], acc, 0, 0, 0);
  acc = __builtin_amdgcn_mfma_f32_16x16x32_bf16(a2, bfrag[2], acc, 0, 0, 0);
  acc = __builtin_amdgcn_mfma_f32_16x16x32_bf16(a3, bfrag[3], acc, 0, 0, 0);
  float aC = ab[c], bC = ab[64 + c], brC = b_rel[c];
#pragma unroll
  for (int reg = 0; reg < 4; ++reg) {
    int r = r0 + quad * 4 + reg;
    float xv = fmaf(raw[(long)r * DIM + c], aC, bC);
    out[(long)r * DIM + c] = fmaxf(acc[reg] + brC + xv, 0.f);
  }
}

extern "C" void kernel_launch(void* const* d_in, const int* in_sizes, int n_in,
                              void* d_out, int out_size, void* d_ws, size_t ws_size,
                              hipStream_t stream) {
  const float* vf = (const float*)d_in[0];
  const float* cf = (const float*)d_in[1];
  const int* es = (const int*)d_in[2];
  const int* ed = (const int*)d_in[3];
  const float* ea = (const float*)d_in[4];
  const float* gn = (const float*)d_in[5];
  const float* bn = (const float*)d_in[6];
  const float* gc = (const float*)d_in[7];
  const float* bc = (const float*)d_in[8];
  const float* n_rel_w = (const float*)d_in[9];
  const float* n_rel_b = (const float*)d_in[10];
  const float* n_root_w = (const float*)d_in[11];
  const float* c_rel_w = (const float*)d_in[12];
  const float* c_rel_b = (const float*)d_in[13];
  const float* c_root_w = (const float*)d_in[14];
  float* out = (float*)d_out;
  int* wsi = (int*)d_ws;
  float* wsf = (float*)d_ws;

  float* stats = wsf + OFF_STATS;
  float* ab = wsf + OFF_AB;
  ushort4* xcb = (ushort4*)(wsi + OFF_XCB);
  ushort4* xnb = (ushort4*)(wsi + OFF_XNB);
  const unsigned short* xcb_s = (const unsigned short*)(wsi + OFF_XCB);
  const unsigned short* xnb_s = (const unsigned short*)(wsi + OFF_XNB);
  const int2* ent_n = (const int2*)(wsi + OFF_ENT_N);
  const int2* ent_c = (const int2*)(wsi + OFF_ENT_C);

  hipMemsetAsync(d_ws, 0, (size_t)WS_ZERO_N * sizeof(int), stream);

  bn_stats_k<<<512, 256, 0, stream>>>(vf, N_VAR, stats);
  bn_stats_k<<<512, 256, 0, stream>>>(cf, N_CSTR, stats + 128);
  bn_finalize_k<<<1, 128, 0, stream>>>(stats, gn, bn, gc, bc, ab);

  cvt_k<<<(N_CSTR * DIM / 4 + 255) / 256, 256, 0, stream>>>((const float4*)cf, ab + 128,
                                                            xcb, N_CSTR * DIM / 4);
  cvt_k<<<(N_VAR * DIM / 4 + 255) / 256, 256, 0, stream>>>((const float4*)vf, ab,
                                                           xnb, N_VAR * DIM / 4);

  bhist_k<<<128, 256, 0, stream>>>((const int4*)es, (const int4*)ed, wsi);
  bscan_k<<<1, 256, 0, stream>>>(wsi);
  passA_k<<<2 * NCHUNK, 256, 0, stream>>>((const int4*)es, (const int4*)ed,
                                          (const float4*)ea, wsi);
  sort_k<<<NBK_T, 256, 0, stream>>>(wsi);

  gmf_k<<<N_VAR / 16, 1024, 0, stream>>>(xcb_s, ent_n, wsi + OFF_OFF_N, vf, ab,
                                         n_rel_w, n_rel_b, n_root_w, out, N_VAR);
  gmf_k<<<N_CSTR / 16, 1024, 0, stream>>>(xnb_s, ent_c, wsi + OFF_OFF_C, cf, ab + 128,
                                          c_rel_w, c_rel_b, c_root_w,
                                          out + (long)N_VAR * DIM, N_CSTR);
}

// Round 4
// 293.880 us; speedup vs baseline: 3.6825x; 1.2207x over previous
//
#include <hip/hip_runtime.h>

#define N_VAR   100000
#define N_CSTR  50000
#define NEDGE   1000000
#define DIM     64

// Coarse buckets: 128 destination nodes each.
#define NBK_N 782           // ceil(100000/128)
#define NBK_C 391           // ceil(50000/128)
#define NBK_T 1173
#define NCHUNK 245          // ceil(1e6/4096) pass-A chunks per side

// ---------------------------------------------------------------------------
// Workspace layout (4-byte units), ~55 MB total:
//   0:         stats      256 (float)  -- zeroed
//   256:       bhist     1280 (int)    -- zeroed
//   1536:      ab         256 (float)
//   1792:      gbase_n    800 (int)
//   2592:      gbase_c    416 (int)
//   3008:      gcur_n     800 (int)
//   3808:      gcur_c     416 (int)
//   4224:      off_node 100004 (int)
//   104228:    off_cstr  50004 (int)
//   154232:    xcb     1600000 (bf16 normalized cstr feats, 50000x64)
//   1754232:   xnb     3200000 (bf16 normalized var  feats, 100000x64)
//   4954232:   ent_n   2000000 (int2)
//   6954232:   ent_c   2000000 (int2)
//   8954232:   aggb    4800000 (bf16 agg means, node rows then cstr rows)
// ---------------------------------------------------------------------------
#define OFF_STATS  0
#define OFF_BHIST  256
#define OFF_AB     1536
#define OFF_GBN    1792
#define OFF_GBC    2592
#define OFF_GCN    3008
#define OFF_GCC    3808
#define OFF_OFF_N  4224
#define OFF_OFF_C  104228
#define OFF_XCB    154232
#define OFF_XNB    1754232
#define OFF_ENT_N  4954232
#define OFF_ENT_C  6954232
#define OFF_AGGB   8954232
#define WS_ZERO_N  1536

typedef __attribute__((ext_vector_type(8))) short bf16x8;
typedef __attribute__((ext_vector_type(4))) float f32x4;

// ---------------------------------------------------------------------------
// BN column stats, both sides in one dispatch (blocks 0..511 var, 512.. cstr).
// ---------------------------------------------------------------------------
__global__ __launch_bounds__(256) void bn_stats_k(const float* __restrict__ vf,
                                                  const float* __restrict__ cf,
                                                  float* __restrict__ stats) {
  int side = blockIdx.x >= 512;
  const float* x = side ? cf : vf;
  int n = side ? N_CSTR : N_VAR;
  float* st = stats + (side ? 128 : 0);
  int b = side ? blockIdx.x - 512 : blockIdx.x;
  int c = threadIdx.x & 63;
  int rg = threadIdx.x >> 6;
  float s = 0.f, q = 0.f;
  for (int r = b * 4 + rg; r < n; r += 512 * 4) {
    float v = x[r * DIM + c];
    s += v;
    q += v * v;
  }
  __shared__ float sb[256], qb[256];
  sb[threadIdx.x] = s;
  qb[threadIdx.x] = q;
  __syncthreads();
  if (rg == 0) {
    s = sb[c] + sb[c + 64] + sb[c + 128] + sb[c + 192];
    q = qb[c] + qb[c + 64] + qb[c + 128] + qb[c + 192];
    atomicAdd(&st[c], s);
    atomicAdd(&st[64 + c], q);
  }
}

__global__ void bn_finalize_k(const float* __restrict__ stats,
                              const float* __restrict__ gn, const float* __restrict__ bn,
                              const float* __restrict__ gc, const float* __restrict__ bc,
                              float* __restrict__ ab) {
  int t = threadIdx.x;  // 0..127
  int c = t & 63;
  bool isC = t >= 64;
  const float* st = stats + (isC ? 128 : 0);
  float n = isC ? (float)N_CSTR : (float)N_VAR;
  float mean = st[c] / n;
  float var = st[64 + c] / n - mean * mean;
  float g = isC ? gc[c] : gn[c];
  float be = isC ? bc[c] : bn[c];
  float a = g * rsqrtf(var + 1e-5f);
  float b = be - mean * a;
  float* o = ab + (isC ? 128 : 0);
  o[c] = a;
  o[64 + c] = b;
}

// ---------------------------------------------------------------------------
// bf16 round-to-nearest-even + normalized table build (both sides, one grid).
// ---------------------------------------------------------------------------
__device__ __forceinline__ unsigned short f2bf(float f) {
  unsigned u = __float_as_uint(f);
  return (unsigned short)((u + 0x7FFFu + ((u >> 16) & 1u)) >> 16);
}

#define NV4 (N_VAR * DIM / 4)   // 1600000
#define NC4 (N_CSTR * DIM / 4)  //  800000

__global__ __launch_bounds__(256) void cvt_k(const float4* __restrict__ vf4,
                                             const float4* __restrict__ cf4,
                                             const float* __restrict__ ab,
                                             ushort4* __restrict__ xnb,
                                             ushort4* __restrict__ xcb) {
  int g4 = blockIdx.x * 256 + threadIdx.x;
  const float4* src4;
  ushort4* dst;
  const float* abp;
  int i4;
  if (g4 < NV4) {
    src4 = vf4; dst = xnb; abp = ab; i4 = g4;
  } else {
    i4 = g4 - NV4;
    if (i4 >= NC4) return;
    src4 = cf4; dst = xcb; abp = ab + 128;
  }
  float4 v = src4[i4];
  int c0 = (i4 << 2) & 63;
  ushort4 o;
  o.x = f2bf(fmaf(v.x, abp[c0 + 0], abp[64 + c0 + 0]));
  o.y = f2bf(fmaf(v.y, abp[c0 + 1], abp[64 + c0 + 1]));
  o.z = f2bf(fmaf(v.z, abp[c0 + 2], abp[64 + c0 + 2]));
  o.w = f2bf(fmaf(v.w, abp[c0 + 3], abp[64 + c0 + 3]));
  dst[i4] = o;
}

// ---------------------------------------------------------------------------
// Coarse bucket histogram (both sides), LDS-aggregated.
// ---------------------------------------------------------------------------
__global__ __launch_bounds__(256) void bhist_k(const int4* __restrict__ es4,
                                               const int4* __restrict__ ed4,
                                               int* __restrict__ ws) {
  __shared__ int h[1280];
  for (int i = threadIdx.x; i < 1280; i += 256) h[i] = 0;
  __syncthreads();
  int stride = gridDim.x * 256;
  for (int i4 = blockIdx.x * 256 + threadIdx.x; i4 < NEDGE / 4; i4 += stride) {
    int4 d = ed4[i4];
    int4 s = es4[i4];
    atomicAdd(&h[d.x >> 7], 1);
    atomicAdd(&h[d.y >> 7], 1);
    atomicAdd(&h[d.z >> 7], 1);
    atomicAdd(&h[d.w >> 7], 1);
    atomicAdd(&h[NBK_N + (s.x >> 7)], 1);
    atomicAdd(&h[NBK_N + (s.y >> 7)], 1);
    atomicAdd(&h[NBK_N + (s.z >> 7)], 1);
    atomicAdd(&h[NBK_N + (s.w >> 7)], 1);
  }
  __syncthreads();
  int* gh = ws + OFF_BHIST;
  for (int i = threadIdx.x; i < NBK_T; i += 256)
    if (h[i]) atomicAdd(&gh[i], h[i]);
}

// ---------------------------------------------------------------------------
// Scan bucket counts -> gbase (+sentinel) and gcur; seed off sentinels. One WG.
// ---------------------------------------------------------------------------
__global__ __launch_bounds__(256) void bscan_k(int* __restrict__ ws) {
  __shared__ int sb[256];
  int t = threadIdx.x;
#pragma unroll
  for (int seg = 0; seg < 2; ++seg) {
    int nbk = seg ? NBK_C : NBK_N;
    const int* h = ws + OFF_BHIST + (seg ? NBK_N : 0);
    int* gb = ws + (seg ? OFF_GBC : OFF_GBN);
    int* gc = ws + (seg ? OFF_GCC : OFF_GCN);
    int base = t * 4;
    int c[4];
    int s0 = 0;
#pragma unroll
    for (int j = 0; j < 4; ++j) {
      c[j] = (base + j < nbk) ? h[base + j] : 0;
      s0 += c[j];
    }
    sb[t] = s0;
    __syncthreads();
    for (int d = 1; d < 256; d <<= 1) {
      int v = (t >= d) ? sb[t - d] : 0;
      __syncthreads();
      sb[t] += v;
      __syncthreads();
    }
    int ex = sb[t] - s0;
#pragma unroll
    for (int j = 0; j < 4; ++j) {
      if (base + j < nbk) {
        gb[base + j] = ex;
        gc[base + j] = ex;
      }
      ex += c[j];
    }
    if (t == 255) gb[nbk] = sb[255];  // sentinel = NEDGE
    __syncthreads();
  }
  if (t == 0) {
    ws[OFF_OFF_N + N_VAR] = NEDGE;
    ws[OFF_OFF_C + N_CSTR] = NEDGE;
  }
}

// ---------------------------------------------------------------------------
// Pass A: LDS multi-split of 4096-edge chunks into coarse buckets.
// ---------------------------------------------------------------------------
__global__ __launch_bounds__(256) void passA_k(const int4* __restrict__ es4,
                                               const int4* __restrict__ ed4,
                                               const float4* __restrict__ ea4,
                                               int* __restrict__ ws) {
  __shared__ int cntL[1024];
  __shared__ int runoffL[1024];
  __shared__ int gblL[1024];
  __shared__ int2 dataL[4096];
  __shared__ unsigned short bidL[4096];
  __shared__ int sbL[256];
  int side = (blockIdx.x >= NCHUNK);
  int chunk = side ? blockIdx.x - NCHUNK : blockIdx.x;
  int nbk = side ? NBK_C : NBK_N;
  int* gcur = ws + (side ? OFF_GCC : OFF_GCN);
  int2* ent = (int2*)(ws + (side ? OFF_ENT_C : OFF_ENT_N));
  int t = threadIdx.x;
  for (int i = t; i < 1024; i += 256) cntL[i] = 0;
  __syncthreads();
  int e0 = chunk * 4096;
  int base4 = chunk * 1024 + t * 4;
  int pk[16];
  int2 pay[16];
#pragma unroll
  for (int j = 0; j < 4; ++j) {
    int i4 = base4 + j;
    if (i4 < NEDGE / 4) {
      int4 sv = es4[i4];
      int4 dv = ed4[i4];
      float4 wv = ea4[i4];
      int ss[4] = {sv.x, sv.y, sv.z, sv.w};
      int dd[4] = {dv.x, dv.y, dv.z, dv.w};
      float ww[4] = {wv.x, wv.y, wv.z, wv.w};
#pragma unroll
      for (int k = 0; k < 4; ++k) {
        int s = ss[k], d = dd[k];
        int b = side ? (s >> 7) : (d >> 7);
        int pl = side ? (d | ((s & 127) << 17)) : (s | ((d & 127) << 17));
        int rank = atomicAdd(&cntL[b], 1);
        pk[j * 4 + k] = b * 4096 + rank;
        pay[j * 4 + k] = make_int2(pl, __float_as_int(ww[k]));
      }
    } else {
#pragma unroll
      for (int k = 0; k < 4; ++k) pk[j * 4 + k] = -1;
    }
  }
  __syncthreads();
  int base = t * 4;
  int c[4];
  int s0 = 0;
#pragma unroll
  for (int j = 0; j < 4; ++j) {
    c[j] = cntL[base + j];
    s0 += c[j];
  }
  sbL[t] = s0;
  __syncthreads();
  for (int d = 1; d < 256; d <<= 1) {
    int v = (t >= d) ? sbL[t - d] : 0;
    __syncthreads();
    sbL[t] += v;
    __syncthreads();
  }
  int ex = sbL[t] - s0;
#pragma unroll
  for (int j = 0; j < 4; ++j) {
    runoffL[base + j] = ex;
    ex += c[j];
  }
  __syncthreads();
  for (int b = t; b < nbk; b += 256) {
    int cc = cntL[b];
    gblL[b] = cc ? atomicAdd(&gcur[b], cc) : 0;
  }
  __syncthreads();
#pragma unroll
  for (int j = 0; j < 16; ++j) {
    if (pk[j] >= 0) {
      int b = pk[j] >> 12;
      int slot = runoffL[b] + (pk[j] & 4095);
      dataL[slot] = pay[j];
      bidL[slot] = (unsigned short)b;
    }
  }
  __syncthreads();
  int chunkN = min(4096, NEDGE - e0);
  for (int i = t; i < chunkN; i += 256) {
    int b = bidL[i];
    ent[gblL[b] + (i - runoffL[b])] = dataL[i];
  }
}

// ---------------------------------------------------------------------------
// Per-bucket in-LDS counting sort -> fully sorted CSR, in place.
// ---------------------------------------------------------------------------
__global__ __launch_bounds__(256) void sort_k(int* __restrict__ ws) {
  __shared__ int2 data[4096];
  __shared__ int hcnt[128], hrank[128];
  __shared__ int sb[128];
  int x = blockIdx.x;
  int side = (x >= NBK_N);
  int bk = side ? x - NBK_N : x;
  const int* gbase = ws + (side ? OFF_GBC : OFF_GBN);
  int2* ent = (int2*)(ws + (side ? OFF_ENT_C : OFF_ENT_N));
  int* off = ws + (side ? OFF_OFF_C : OFF_OFF_N);
  int n = side ? N_CSTR : N_VAR;
  int t = threadIdx.x;
  int beg = gbase[bk], end = gbase[bk + 1];
  int cnt = end - beg;
  if (t < 128) hcnt[t] = 0;
  __syncthreads();
  for (int i = t; i < cnt; i += 256) {
    int2 e = ent[beg + i];
    data[i] = e;
    atomicAdd(&hcnt[(e.x >> 17) & 127], 1);
  }
  __syncthreads();
  if (t < 128) sb[t] = hcnt[t];
  __syncthreads();
  for (int d = 1; d < 128; d <<= 1) {
    int v = 0;
    if (t < 128 && t >= d) v = sb[t - d];
    __syncthreads();
    if (t < 128) sb[t] += v;
    __syncthreads();
  }
  if (t < 128) {
    int ex = sb[t] - hcnt[t];
    hrank[t] = ex;
    int r = bk * 128 + t;
    if (r < n) off[r] = beg + ex;
  }
  __syncthreads();
  for (int i = t; i < cnt; i += 256) {
    int2 e = data[i];
    int dl = (e.x >> 17) & 127;
    int pos = atomicAdd(&hrank[dl], 1);
    ent[beg + pos] = make_int2(e.x & 0x1FFFF, e.y);
  }
}

// ---------------------------------------------------------------------------
// Gather from sorted CSR (both sides, one dispatch): one wave per row,
// lane = column, unroll-8 — the proven round-0 TLP structure (4 waves / 256-thr
// WG, no barriers, 8 WGs/CU). Output: bf16 mean row into aggb (halves agg
// traffic vs f32; f2bf here is bit-identical to the epilogue's old f2bf).
// Blocks 0..24999 -> node rows (gather cstr feats); 25000..37499 -> cstr rows.
// ---------------------------------------------------------------------------
__global__ __launch_bounds__(256) void gather_k(
    const unsigned short* __restrict__ xcb, const unsigned short* __restrict__ xnb,
    const int2* __restrict__ ent_n, const int2* __restrict__ ent_c,
    const int* __restrict__ off_n, const int* __restrict__ off_c,
    unsigned short* __restrict__ aggb) {
  int lane = threadIdx.x & 63;
  int gb = blockIdx.x;
  int side = gb >= 25000;
  int lb = side ? gb - 25000 : gb;
  int r = __builtin_amdgcn_readfirstlane(lb * 4 + (threadIdx.x >> 6));
  const unsigned short* tab = side ? xnb : xcb;
  const int2* ent = side ? ent_c : ent_n;
  const int* off = side ? off_c : off_n;
  long orow = side ? (long)N_VAR + r : (long)r;
  int beg = off[r], end = off[r + 1];
  float acc0 = 0.f, acc1 = 0.f;
  int e = beg;
#define BF(hv) __uint_as_float(((unsigned)(hv)) << 16)
  if (e < end && (e & 1)) {
    int2 p = ent[e];
    acc0 = fmaf(BF(tab[p.x * DIM + lane]), __int_as_float(p.y), acc0);
    ++e;
  }
  for (; e + 8 <= end; e += 8) {
    int4 p0 = *reinterpret_cast<const int4*>(&ent[e]);
    int4 p1 = *reinterpret_cast<const int4*>(&ent[e + 2]);
    int4 p2 = *reinterpret_cast<const int4*>(&ent[e + 4]);
    int4 p3 = *reinterpret_cast<const int4*>(&ent[e + 6]);
    float v0 = BF(tab[p0.x * DIM + lane]);
    float v1 = BF(tab[p0.z * DIM + lane]);
    float v2 = BF(tab[p1.x * DIM + lane]);
    float v3 = BF(tab[p1.z * DIM + lane]);
    float v4 = BF(tab[p2.x * DIM + lane]);
    float v5 = BF(tab[p2.z * DIM + lane]);
    float v6 = BF(tab[p3.x * DIM + lane]);
    float v7 = BF(tab[p3.z * DIM + lane]);
    acc0 = fmaf(v0, __int_as_float(p0.y), acc0);
    acc1 = fmaf(v1, __int_as_float(p0.w), acc1);
    acc0 = fmaf(v2, __int_as_float(p1.y), acc0);
    acc1 = fmaf(v3, __int_as_float(p1.w), acc1);
    acc0 = fmaf(v4, __int_as_float(p2.y), acc0);
    acc1 = fmaf(v5, __int_as_float(p2.w), acc1);
    acc0 = fmaf(v6, __int_as_float(p3.y), acc0);
    acc1 = fmaf(v7, __int_as_float(p3.w), acc1);
  }
  for (; e + 2 <= end; e += 2) {
    int4 p = *reinterpret_cast<const int4*>(&ent[e]);
    acc0 = fmaf(BF(tab[p.x * DIM + lane]), __int_as_float(p.y), acc0);
    acc1 = fmaf(BF(tab[p.z * DIM + lane]), __int_as_float(p.w), acc1);
  }
  if (e < end) {
    int2 p = ent[e];
    acc0 = fmaf(BF(tab[p.x * DIM + lane]), __int_as_float(p.y), acc0);
  }
#undef BF
  float mean = (acc0 + acc1) / fmaxf((float)(end - beg), 1.f);
  aggb[orow * DIM + lane] = f2bf(mean);
}

// ---------------------------------------------------------------------------
// MFMA output epilogue (both sides, one dispatch):
//   out[r][c] = relu( [aggb[r] | xt[r]] (K=128) . [w_rel[c] ; w_root[c]]
//               + b_rel[c] + xv[r][c] )
// A-fragments are direct 16B bf16x8 loads from aggb / xt (bit-identical to the
// old f2bf-recompute path since cvt_k/gather_k stored exactly those values).
// Residual xv recomputed in f32 from raw for exactness. One 16-row tile per
// wave per iteration; 16 MFMAs/tile. A: row=l16, k=quad*8+j; D: col=lane&15,
// row=quad*4+reg (HW-verified mappings). Blocks 0..639 node, 640..959 cstr.
// ---------------------------------------------------------------------------
__global__ __launch_bounds__(256) void out_k(
    const unsigned short* __restrict__ aggb,
    const unsigned short* __restrict__ xnb, const unsigned short* __restrict__ xcb,
    const float* __restrict__ vf, const float* __restrict__ cf,
    const float* __restrict__ ab,
    const float* __restrict__ nrel_w, const float* __restrict__ nrel_b,
    const float* __restrict__ nroot_w,
    const float* __restrict__ crel_w, const float* __restrict__ crel_b,
    const float* __restrict__ croot_w,
    float* __restrict__ out) {
  int t = threadIdx.x;
  int lane = t & 63, wv = t >> 6;
  int quad = lane >> 4, l16 = lane & 15;
  int side = blockIdx.x >= 640;
  int b = side ? blockIdx.x - 640 : blockIdx.x;
  int nblk = side ? 320 : 640;
  int tiles = (side ? N_CSTR : N_VAR) >> 4;
  const unsigned short* xt = side ? xcb : xnb;
  const unsigned short* ag = aggb + (side ? (long)N_VAR * DIM : 0);
  const float* raw = side ? cf : vf;
  const float* abp = ab + (side ? 128 : 0);
  const float* w_rel = side ? crel_w : nrel_w;
  const float* b_rel = side ? crel_b : nrel_b;
  const float* w_root = side ? croot_w : nroot_w;
  float* o = out + (side ? (long)N_VAR * DIM : 0);

  // B fragments: bfrag[nt][kc] holds B[k=kc*32+quad*8+j][n=nt*16+l16]
  //            = W128[n][k], W128[c] = concat(w_rel[c][:], w_root[c][:]).
  bf16x8 bfrag[4][4];
#pragma unroll
  for (int nt = 0; nt < 4; ++nt) {
    int c = nt * 16 + l16;
#pragma unroll
    for (int kc = 0; kc < 4; ++kc) {
      int bk = kc * 32 + quad * 8;
      const float* wsrc = (bk < 64) ? (w_rel + c * 64 + bk) : (w_root + c * 64 + bk - 64);
      bf16x8 f;
#pragma unroll
      for (int j = 0; j < 8; ++j) f[j] = (short)f2bf(wsrc[j]);
      bfrag[nt][kc] = f;
    }
  }

  for (int tile = b * 4 + wv; tile < tiles; tile += nblk * 4) {
    int r0 = tile << 4;
    long arow = (long)(r0 + l16) * DIM;
    bf16x8 a0 = *reinterpret_cast<const bf16x8*>(&ag[arow + quad * 8]);
    bf16x8 a1 = *reinterpret_cast<const bf16x8*>(&ag[arow + 32 + quad * 8]);
    bf16x8 a2 = *reinterpret_cast<const bf16x8*>(&xt[arow + quad * 8]);
    bf16x8 a3 = *reinterpret_cast<const bf16x8*>(&xt[arow + 32 + quad * 8]);
    f32x4 acc[4];
#pragma unroll
    for (int nt = 0; nt < 4; ++nt) {
      acc[nt] = (f32x4){0.f, 0.f, 0.f, 0.f};
      acc[nt] = __builtin_amdgcn_mfma_f32_16x16x32_bf16(a0, bfrag[nt][0], acc[nt], 0, 0, 0);
      acc[nt] = __builtin_amdgcn_mfma_f32_16x16x32_bf16(a1, bfrag[nt][1], acc[nt], 0, 0, 0);
      acc[nt] = __builtin_amdgcn_mfma_f32_16x16x32_bf16(a2, bfrag[nt][2], acc[nt], 0, 0, 0);
      acc[nt] = __builtin_amdgcn_mfma_f32_16x16x32_bf16(a3, bfrag[nt][3], acc[nt], 0, 0, 0);
    }
#pragma unroll
    for (int nt = 0; nt < 4; ++nt) {
      int c = nt * 16 + l16;
      float aC = abp[c], bC = abp[64 + c], brC = b_rel[c];
#pragma unroll
      for (int reg = 0; reg < 4; ++reg) {
        int r = r0 + quad * 4 + reg;
        float xv = fmaf(raw[(long)r * DIM + c], aC, bC);
        o[(long)r * DIM + c] = fmaxf(acc[nt][reg] + brC + xv, 0.f);
      }
    }
  }
}

extern "C" void kernel_launch(void* const* d_in, const int* in_sizes, int n_in,
                              void* d_out, int out_size, void* d_ws, size_t ws_size,
                              hipStream_t stream) {
  const float* vf = (const float*)d_in[0];
  const float* cf = (const float*)d_in[1];
  const int* es = (const int*)d_in[2];
  const int* ed = (const int*)d_in[3];
  const float* ea = (const float*)d_in[4];
  const float* gn = (const float*)d_in[5];
  const float* bn = (const float*)d_in[6];
  const float* gc = (const float*)d_in[7];
  const float* bc = (const float*)d_in[8];
  const float* n_rel_w = (const float*)d_in[9];
  const float* n_rel_b = (const float*)d_in[10];
  const float* n_root_w = (const float*)d_in[11];
  const float* c_rel_w = (const float*)d_in[12];
  const float* c_rel_b = (const float*)d_in[13];
  const float* c_root_w = (const float*)d_in[14];
  float* out = (float*)d_out;
  int* wsi = (int*)d_ws;
  float* wsf = (float*)d_ws;

  float* stats = wsf + OFF_STATS;
  float* ab = wsf + OFF_AB;
  ushort4* xcb4 = (ushort4*)(wsi + OFF_XCB);
  ushort4* xnb4 = (ushort4*)(wsi + OFF_XNB);
  const unsigned short* xcb_s = (const unsigned short*)(wsi + OFF_XCB);
  const unsigned short* xnb_s = (const unsigned short*)(wsi + OFF_XNB);
  const int2* ent_n = (const int2*)(wsi + OFF_ENT_N);
  const int2* ent_c = (const int2*)(wsi + OFF_ENT_C);
  unsigned short* aggb = (unsigned short*)(wsi + OFF_AGGB);

  hipMemsetAsync(d_ws, 0, (size_t)WS_ZERO_N * sizeof(int), stream);

  bn_stats_k<<<1024, 256, 0, stream>>>(vf, cf, stats);
  bn_finalize_k<<<1, 128, 0, stream>>>(stats, gn, bn, gc, bc, ab);

  cvt_k<<<(NV4 + NC4 + 255) / 256, 256, 0, stream>>>((const float4*)vf, (const float4*)cf,
                                                     ab, xnb4, xcb4);

  bhist_k<<<128, 256, 0, stream>>>((const int4*)es, (const int4*)ed, wsi);
  bscan_k<<<1, 256, 0, stream>>>(wsi);
  passA_k<<<2 * NCHUNK, 256, 0, stream>>>((const int4*)es, (const int4*)ed,
                                          (const float4*)ea, wsi);
  sort_k<<<NBK_T, 256, 0, stream>>>(wsi);

  gather_k<<<37500, 256, 0, stream>>>(xcb_s, xnb_s, ent_n, ent_c,
                                      wsi + OFF_OFF_N, wsi + OFF_OFF_C, aggb);

  out_k<<<960, 256, 0, stream>>>(aggb, xnb_s, xcb_s, vf, cf, ab,
                                 n_rel_w, n_rel_b, n_root_w,
                                 c_rel_w, c_rel_b, c_root_w, out);
}

// Round 5
// 288.495 us; speedup vs baseline: 3.7513x; 1.0187x over previous
//
#include <hip/hip_runtime.h>

#define N_VAR   100000
#define N_CSTR  50000
#define NEDGE   1000000
#define DIM     64

// Coarse buckets: 128 destination nodes each.
#define NBK_N 782           // ceil(100000/128)
#define NBK_C 391           // ceil(50000/128)
#define NBK_T 1173
#define NCHUNK 245          // ceil(1e6/4096) pass-A chunks per side

// ---------------------------------------------------------------------------
// Workspace layout (4-byte units), ~55 MB total (see round-4; unchanged).
// ---------------------------------------------------------------------------
#define OFF_STATS  0
#define OFF_BHIST  256
#define OFF_AB     1536
#define OFF_GBN    1792
#define OFF_GBC    2592
#define OFF_GCN    3008
#define OFF_GCC    3808
#define OFF_OFF_N  4224
#define OFF_OFF_C  104228
#define OFF_XCB    154232
#define OFF_XNB    1754232
#define OFF_ENT_N  4954232
#define OFF_ENT_C  6954232
#define OFF_AGGB   8954232
#define WS_ZERO_N  1536

typedef __attribute__((ext_vector_type(8))) short bf16x8;
typedef __attribute__((ext_vector_type(4))) float f32x4;

__device__ __forceinline__ unsigned short f2bf(float f) {
  unsigned u = __float_as_uint(f);
  return (unsigned short)((u + 0x7FFFu + ((u >> 16) & 1u)) >> 16);
}

#define NV4 (N_VAR * DIM / 4)   // 1600000
#define NC4 (N_CSTR * DIM / 4)  //  800000

// ---------------------------------------------------------------------------
// pre_k: blocks 0..127 = bhist (coarse bucket histogram, LDS-aggregated);
//        blocks 128..1151 = bn_stats (both sides). Independent chains overlap
//        in one dispatch. Shared 5 KB LDS union.
// ---------------------------------------------------------------------------
__global__ __launch_bounds__(256) void pre_k(const float* __restrict__ vf,
                                             const float* __restrict__ cf,
                                             const int4* __restrict__ es4,
                                             const int4* __restrict__ ed4,
                                             int* __restrict__ ws) {
  __shared__ int smem[1280];
  int t = threadIdx.x;
  if (blockIdx.x < 128) {
    // ---- bhist ----
    int* h = smem;
    for (int i = t; i < 1280; i += 256) h[i] = 0;
    __syncthreads();
    for (int i4 = blockIdx.x * 256 + t; i4 < NEDGE / 4; i4 += 128 * 256) {
      int4 d = ed4[i4];
      int4 s = es4[i4];
      atomicAdd(&h[d.x >> 7], 1);
      atomicAdd(&h[d.y >> 7], 1);
      atomicAdd(&h[d.z >> 7], 1);
      atomicAdd(&h[d.w >> 7], 1);
      atomicAdd(&h[NBK_N + (s.x >> 7)], 1);
      atomicAdd(&h[NBK_N + (s.y >> 7)], 1);
      atomicAdd(&h[NBK_N + (s.z >> 7)], 1);
      atomicAdd(&h[NBK_N + (s.w >> 7)], 1);
    }
    __syncthreads();
    int* gh = ws + OFF_BHIST;
    for (int i = t; i < NBK_T; i += 256)
      if (h[i]) atomicAdd(&gh[i], h[i]);
  } else {
    // ---- bn_stats ----
    int b = blockIdx.x - 128;
    int side = b >= 512;
    const float* x = side ? cf : vf;
    int n = side ? N_CSTR : N_VAR;
    float* st = (float*)(ws + OFF_STATS) + (side ? 128 : 0);
    if (side) b -= 512;
    int c = t & 63;
    int rg = t >> 6;
    float s = 0.f, q = 0.f;
    for (int r = b * 4 + rg; r < n; r += 512 * 4) {
      float v = x[r * DIM + c];
      s += v;
      q += v * v;
    }
    float* sb = (float*)smem;
    float* qb = sb + 256;
    sb[t] = s;
    qb[t] = q;
    __syncthreads();
    if (rg == 0) {
      s = sb[c] + sb[c + 64] + sb[c + 128] + sb[c + 192];
      q = qb[c] + qb[c + 64] + qb[c + 128] + qb[c + 192];
      atomicAdd(&st[c], s);
      atomicAdd(&st[64 + c], q);
    }
  }
}

// ---------------------------------------------------------------------------
// fin_scan_k: one block. Phase 1 = bscan (bucket count scan -> gbase/gcur,
// sentinels); Phase 2 = bn_finalize (threads 0..127). Saves a dispatch.
// ---------------------------------------------------------------------------
__global__ __launch_bounds__(256) void fin_scan_k(
    int* __restrict__ ws, const float* __restrict__ gn, const float* __restrict__ bn,
    const float* __restrict__ gc, const float* __restrict__ bc) {
  __shared__ int sb[256];
  int t = threadIdx.x;
#pragma unroll
  for (int seg = 0; seg < 2; ++seg) {
    int nbk = seg ? NBK_C : NBK_N;
    const int* h = ws + OFF_BHIST + (seg ? NBK_N : 0);
    int* gb = ws + (seg ? OFF_GBC : OFF_GBN);
    int* gcur = ws + (seg ? OFF_GCC : OFF_GCN);
    int base = t * 4;
    int c[4];
    int s0 = 0;
#pragma unroll
    for (int j = 0; j < 4; ++j) {
      c[j] = (base + j < nbk) ? h[base + j] : 0;
      s0 += c[j];
    }
    sb[t] = s0;
    __syncthreads();
    for (int d = 1; d < 256; d <<= 1) {
      int v = (t >= d) ? sb[t - d] : 0;
      __syncthreads();
      sb[t] += v;
      __syncthreads();
    }
    int ex = sb[t] - s0;
#pragma unroll
    for (int j = 0; j < 4; ++j) {
      if (base + j < nbk) {
        gb[base + j] = ex;
        gcur[base + j] = ex;
      }
      ex += c[j];
    }
    if (t == 255) gb[nbk] = sb[255];  // sentinel = NEDGE
    __syncthreads();
  }
  if (t == 0) {
    ws[OFF_OFF_N + N_VAR] = NEDGE;
    ws[OFF_OFF_C + N_CSTR] = NEDGE;
  }
  // ---- bn_finalize ----
  if (t < 128) {
    const float* stats = (const float*)(ws + OFF_STATS);
    float* ab = (float*)(ws + OFF_AB);
    int c = t & 63;
    bool isC = t >= 64;
    const float* st = stats + (isC ? 128 : 0);
    float n = isC ? (float)N_CSTR : (float)N_VAR;
    float mean = st[c] / n;
    float var = st[64 + c] / n - mean * mean;
    float g = isC ? gc[c] : gn[c];
    float be = isC ? bc[c] : bn[c];
    float a = g * rsqrtf(var + 1e-5f);
    float b = be - mean * a;
    float* o = ab + (isC ? 128 : 0);
    o[c] = a;
    o[64 + c] = b;
  }
}

// ---------------------------------------------------------------------------
// mid_k: blocks 0..489 = passA (LDS multi-split into coarse buckets, dispatched
// first); blocks 490.. = cvt (bf16 normalized table build, 4 chunks/thread for
// MLP at the 3-block/CU LDS cap). 54272 B LDS union (3 blocks/CU).
// ---------------------------------------------------------------------------
#define CVT_S (2344 * 256)  // chunk stride = 600064; 4*S >= NV4+NC4

__global__ __launch_bounds__(256) void mid_k(const int4* __restrict__ es4,
                                             const int4* __restrict__ ed4,
                                             const float4* __restrict__ ea4,
                                             const float4* __restrict__ vf4,
                                             const float4* __restrict__ cf4,
                                             int* __restrict__ ws) {
  __shared__ int smem[13568];  // 54272 B
  int t = threadIdx.x;
  if (blockIdx.x < 2 * NCHUNK) {
    // ---- passA ----
    int* cntL = smem;            // 1024
    int* runoffL = smem + 1024;  // 1024
    int* gblL = smem + 2048;     // 1024
    int* sbL = smem + 3072;      // 256
    int2* dataL = (int2*)(smem + 3328);                 // 4096 int2
    unsigned short* bidL = (unsigned short*)(smem + 11520);  // 4096 u16
    int side = (blockIdx.x >= NCHUNK);
    int chunk = side ? blockIdx.x - NCHUNK : blockIdx.x;
    int nbk = side ? NBK_C : NBK_N;
    int* gcur = ws + (side ? OFF_GCC : OFF_GCN);
    int2* ent = (int2*)(ws + (side ? OFF_ENT_C : OFF_ENT_N));
    for (int i = t; i < 1024; i += 256) cntL[i] = 0;
    __syncthreads();
    int e0 = chunk * 4096;
    int base4 = chunk * 1024 + t * 4;
    int pk[16];
    int2 pay[16];
#pragma unroll
    for (int j = 0; j < 4; ++j) {
      int i4 = base4 + j;
      if (i4 < NEDGE / 4) {
        int4 sv = es4[i4];
        int4 dv = ed4[i4];
        float4 wv = ea4[i4];
        int ss[4] = {sv.x, sv.y, sv.z, sv.w};
        int dd[4] = {dv.x, dv.y, dv.z, dv.w};
        float ww[4] = {wv.x, wv.y, wv.z, wv.w};
#pragma unroll
        for (int k = 0; k < 4; ++k) {
          int s = ss[k], d = dd[k];
          int b = side ? (s >> 7) : (d >> 7);
          int pl = side ? (d | ((s & 127) << 17)) : (s | ((d & 127) << 17));
          int rank = atomicAdd(&cntL[b], 1);
          pk[j * 4 + k] = b * 4096 + rank;
          pay[j * 4 + k] = make_int2(pl, __float_as_int(ww[k]));
        }
      } else {
#pragma unroll
        for (int k = 0; k < 4; ++k) pk[j * 4 + k] = -1;
      }
    }
    __syncthreads();
    int base = t * 4;
    int c[4];
    int s0 = 0;
#pragma unroll
    for (int j = 0; j < 4; ++j) {
      c[j] = cntL[base + j];
      s0 += c[j];
    }
    sbL[t] = s0;
    __syncthreads();
    for (int d = 1; d < 256; d <<= 1) {
      int v = (t >= d) ? sbL[t - d] : 0;
      __syncthreads();
      sbL[t] += v;
      __syncthreads();
    }
    int ex = sbL[t] - s0;
#pragma unroll
    for (int j = 0; j < 4; ++j) {
      runoffL[base + j] = ex;
      ex += c[j];
    }
    __syncthreads();
    for (int b = t; b < nbk; b += 256) {
      int cc = cntL[b];
      gblL[b] = cc ? atomicAdd(&gcur[b], cc) : 0;
    }
    __syncthreads();
#pragma unroll
    for (int j = 0; j < 16; ++j) {
      if (pk[j] >= 0) {
        int b = pk[j] >> 12;
        int slot = runoffL[b] + (pk[j] & 4095);
        dataL[slot] = pay[j];
        bidL[slot] = (unsigned short)b;
      }
    }
    __syncthreads();
    int chunkN = min(4096, NEDGE - e0);
    for (int i = t; i < chunkN; i += 256) {
      int b = bidL[i];
      ent[gblL[b] + (i - runoffL[b])] = dataL[i];
    }
  } else {
    // ---- cvt ----
    const float* ab = (const float*)(ws + OFF_AB);
    ushort4* xnb = (ushort4*)(ws + OFF_XNB);
    ushort4* xcb = (ushort4*)(ws + OFF_XCB);
    int g0 = (blockIdx.x - 2 * NCHUNK) * 256 + t;
#pragma unroll
    for (int ii = 0; ii < 4; ++ii) {
      int i4 = g0 + ii * CVT_S;
      if (i4 >= NV4 + NC4) break;
      const float4* src4;
      ushort4* dst;
      const float* abp;
      int j4;
      if (i4 < NV4) {
        src4 = vf4; dst = xnb; abp = ab; j4 = i4;
      } else {
        j4 = i4 - NV4;
        src4 = cf4; dst = xcb; abp = ab + 128;
      }
      float4 v = src4[j4];
      int c0 = (j4 << 2) & 63;
      ushort4 o;
      o.x = f2bf(fmaf(v.x, abp[c0 + 0], abp[64 + c0 + 0]));
      o.y = f2bf(fmaf(v.y, abp[c0 + 1], abp[64 + c0 + 1]));
      o.z = f2bf(fmaf(v.z, abp[c0 + 2], abp[64 + c0 + 2]));
      o.w = f2bf(fmaf(v.w, abp[c0 + 3], abp[64 + c0 + 3]));
      dst[j4] = o;
    }
  }
}

// ---------------------------------------------------------------------------
// Per-bucket in-LDS counting sort -> fully sorted CSR, in place.
// ---------------------------------------------------------------------------
__global__ __launch_bounds__(256) void sort_k(int* __restrict__ ws) {
  __shared__ int2 data[4096];
  __shared__ int hcnt[128], hrank[128];
  __shared__ int sb[128];
  int x = blockIdx.x;
  int side = (x >= NBK_N);
  int bk = side ? x - NBK_N : x;
  const int* gbase = ws + (side ? OFF_GBC : OFF_GBN);
  int2* ent = (int2*)(ws + (side ? OFF_ENT_C : OFF_ENT_N));
  int* off = ws + (side ? OFF_OFF_C : OFF_OFF_N);
  int n = side ? N_CSTR : N_VAR;
  int t = threadIdx.x;
  int beg = gbase[bk], end = gbase[bk + 1];
  int cnt = end - beg;
  if (t < 128) hcnt[t] = 0;
  __syncthreads();
  for (int i = t; i < cnt; i += 256) {
    int2 e = ent[beg + i];
    data[i] = e;
    atomicAdd(&hcnt[(e.x >> 17) & 127], 1);
  }
  __syncthreads();
  if (t < 128) sb[t] = hcnt[t];
  __syncthreads();
  for (int d = 1; d < 128; d <<= 1) {
    int v = 0;
    if (t < 128 && t >= d) v = sb[t - d];
    __syncthreads();
    if (t < 128) sb[t] += v;
    __syncthreads();
  }
  if (t < 128) {
    int ex = sb[t] - hcnt[t];
    hrank[t] = ex;
    int r = bk * 128 + t;
    if (r < n) off[r] = beg + ex;
  }
  __syncthreads();
  for (int i = t; i < cnt; i += 256) {
    int2 e = data[i];
    int dl = (e.x >> 17) & 127;
    int pos = atomicAdd(&hrank[dl], 1);
    ent[beg + pos] = make_int2(e.x & 0x1FFFF, e.y);
  }
}

// ---------------------------------------------------------------------------
// Gather from sorted CSR (both sides, one dispatch): one wave per row, lane =
// column, software-pipelined unroll-8 (next ent burst prefetched before the
// current burst's FMAs so ent latency hides under table-load latency).
// Output: bf16 mean row into aggb.
// Blocks 0..24999 -> node rows (gather cstr feats); 25000..37499 -> cstr rows.
// ---------------------------------------------------------------------------
__global__ __launch_bounds__(256) void gather_k(
    const unsigned short* __restrict__ xcb, const unsigned short* __restrict__ xnb,
    const int2* __restrict__ ent_n, const int2* __restrict__ ent_c,
    const int* __restrict__ off_n, const int* __restrict__ off_c,
    unsigned short* __restrict__ aggb) {
  int lane = threadIdx.x & 63;
  int gb = blockIdx.x;
  int side = gb >= 25000;
  int lb = side ? gb - 25000 : gb;
  int r = __builtin_amdgcn_readfirstlane(lb * 4 + (threadIdx.x >> 6));
  const unsigned short* tab = side ? xnb : xcb;
  const int2* ent = side ? ent_c : ent_n;
  const int* off = side ? off_c : off_n;
  long orow = side ? (long)N_VAR + r : (long)r;
  int beg = off[r], end = off[r + 1];
  float acc0 = 0.f, acc1 = 0.f;
  int e = beg;
#define BF(hv) __uint_as_float(((unsigned)(hv)) << 16)
  if (e < end && (e & 1)) {
    int2 p = ent[e];
    acc0 = fmaf(BF(tab[p.x * DIM + lane]), __int_as_float(p.y), acc0);
    ++e;
  }
  int nb = (end - e) >> 3;
  if (nb > 0) {
    int4 q0 = *reinterpret_cast<const int4*>(&ent[e]);
    int4 q1 = *reinterpret_cast<const int4*>(&ent[e + 2]);
    int4 q2 = *reinterpret_cast<const int4*>(&ent[e + 4]);
    int4 q3 = *reinterpret_cast<const int4*>(&ent[e + 6]);
    for (int bi = 0; bi < nb; ++bi) {
      int4 p0 = q0, p1 = q1, p2 = q2, p3 = q3;
      e += 8;
      if (bi + 1 < nb) {
        q0 = *reinterpret_cast<const int4*>(&ent[e]);
        q1 = *reinterpret_cast<const int4*>(&ent[e + 2]);
        q2 = *reinterpret_cast<const int4*>(&ent[e + 4]);
        q3 = *reinterpret_cast<const int4*>(&ent[e + 6]);
      }
      float v0 = BF(tab[p0.x * DIM + lane]);
      float v1 = BF(tab[p0.z * DIM + lane]);
      float v2 = BF(tab[p1.x * DIM + lane]);
      float v3 = BF(tab[p1.z * DIM + lane]);
      float v4 = BF(tab[p2.x * DIM + lane]);
      float v5 = BF(tab[p2.z * DIM + lane]);
      float v6 = BF(tab[p3.x * DIM + lane]);
      float v7 = BF(tab[p3.z * DIM + lane]);
      acc0 = fmaf(v0, __int_as_float(p0.y), acc0);
      acc1 = fmaf(v1, __int_as_float(p0.w), acc1);
      acc0 = fmaf(v2, __int_as_float(p1.y), acc0);
      acc1 = fmaf(v3, __int_as_float(p1.w), acc1);
      acc0 = fmaf(v4, __int_as_float(p2.y), acc0);
      acc1 = fmaf(v5, __int_as_float(p2.w), acc1);
      acc0 = fmaf(v6, __int_as_float(p3.y), acc0);
      acc1 = fmaf(v7, __int_as_float(p3.w), acc1);
    }
  }
  for (; e + 2 <= end; e += 2) {
    int4 p = *reinterpret_cast<const int4*>(&ent[e]);
    acc0 = fmaf(BF(tab[p.x * DIM + lane]), __int_as_float(p.y), acc0);
    acc1 = fmaf(BF(tab[p.z * DIM + lane]), __int_as_float(p.w), acc1);
  }
  if (e < end) {
    int2 p = ent[e];
    acc0 = fmaf(BF(tab[p.x * DIM + lane]), __int_as_float(p.y), acc0);
  }
#undef BF
  float mean = (acc0 + acc1) / fmaxf((float)(end - beg), 1.f);
  aggb[orow * DIM + lane] = f2bf(mean);
}

// ---------------------------------------------------------------------------
// MFMA output epilogue (both sides, one dispatch) -- unchanged from round 4.
// ---------------------------------------------------------------------------
__global__ __launch_bounds__(256) void out_k(
    const unsigned short* __restrict__ aggb,
    const unsigned short* __restrict__ xnb, const unsigned short* __restrict__ xcb,
    const float* __restrict__ vf, const float* __restrict__ cf,
    const float* __restrict__ ab,
    const float* __restrict__ nrel_w, const float* __restrict__ nrel_b,
    const float* __restrict__ nroot_w,
    const float* __restrict__ crel_w, const float* __restrict__ crel_b,
    const float* __restrict__ croot_w,
    float* __restrict__ out) {
  int t = threadIdx.x;
  int lane = t & 63, wv = t >> 6;
  int quad = lane >> 4, l16 = lane & 15;
  int side = blockIdx.x >= 640;
  int b = side ? blockIdx.x - 640 : blockIdx.x;
  int nblk = side ? 320 : 640;
  int tiles = (side ? N_CSTR : N_VAR) >> 4;
  const unsigned short* xt = side ? xcb : xnb;
  const unsigned short* ag = aggb + (side ? (long)N_VAR * DIM : 0);
  const float* raw = side ? cf : vf;
  const float* abp = ab + (side ? 128 : 0);
  const float* w_rel = side ? crel_w : nrel_w;
  const float* b_rel = side ? crel_b : nrel_b;
  const float* w_root = side ? croot_w : nroot_w;
  float* o = out + (side ? (long)N_VAR * DIM : 0);

  // B fragments: bfrag[nt][kc] holds B[k=kc*32+quad*8+j][n=nt*16+l16]
  //            = W128[n][k], W128[c] = concat(w_rel[c][:], w_root[c][:]).
  bf16x8 bfrag[4][4];
#pragma unroll
  for (int nt = 0; nt < 4; ++nt) {
    int c = nt * 16 + l16;
#pragma unroll
    for (int kc = 0; kc < 4; ++kc) {
      int bk = kc * 32 + quad * 8;
      const float* wsrc = (bk < 64) ? (w_rel + c * 64 + bk) : (w_root + c * 64 + bk - 64);
      bf16x8 f;
#pragma unroll
      for (int j = 0; j < 8; ++j) f[j] = (short)f2bf(wsrc[j]);
      bfrag[nt][kc] = f;
    }
  }

  for (int tile = b * 4 + wv; tile < tiles; tile += nblk * 4) {
    int r0 = tile << 4;
    long arow = (long)(r0 + l16) * DIM;
    bf16x8 a0 = *reinterpret_cast<const bf16x8*>(&ag[arow + quad * 8]);
    bf16x8 a1 = *reinterpret_cast<const bf16x8*>(&ag[arow + 32 + quad * 8]);
    bf16x8 a2 = *reinterpret_cast<const bf16x8*>(&xt[arow + quad * 8]);
    bf16x8 a3 = *reinterpret_cast<const bf16x8*>(&xt[arow + 32 + quad * 8]);
    f32x4 acc[4];
#pragma unroll
    for (int nt = 0; nt < 4; ++nt) {
      acc[nt] = (f32x4){0.f, 0.f, 0.f, 0.f};
      acc[nt] = __builtin_amdgcn_mfma_f32_16x16x32_bf16(a0, bfrag[nt][0], acc[nt], 0, 0, 0);
      acc[nt] = __builtin_amdgcn_mfma_f32_16x16x32_bf16(a1, bfrag[nt][1], acc[nt], 0, 0, 0);
      acc[nt] = __builtin_amdgcn_mfma_f32_16x16x32_bf16(a2, bfrag[nt][2], acc[nt], 0, 0, 0);
      acc[nt] = __builtin_amdgcn_mfma_f32_16x16x32_bf16(a3, bfrag[nt][3], acc[nt], 0, 0, 0);
    }
#pragma unroll
    for (int nt = 0; nt < 4; ++nt) {
      int c = nt * 16 + l16;
      float aC = abp[c], bC = abp[64 + c], brC = b_rel[c];
#pragma unroll
      for (int reg = 0; reg < 4; ++reg) {
        int r = r0 + quad * 4 + reg;
        float xv = fmaf(raw[(long)r * DIM + c], aC, bC);
        o[(long)r * DIM + c] = fmaxf(acc[nt][reg] + brC + xv, 0.f);
      }
    }
  }
}

extern "C" void kernel_launch(void* const* d_in, const int* in_sizes, int n_in,
                              void* d_out, int out_size, void* d_ws, size_t ws_size,
                              hipStream_t stream) {
  const float* vf = (const float*)d_in[0];
  const float* cf = (const float*)d_in[1];
  const int* es = (const int*)d_in[2];
  const int* ed = (const int*)d_in[3];
  const float* ea = (const float*)d_in[4];
  const float* gn = (const float*)d_in[5];
  const float* bn = (const float*)d_in[6];
  const float* gc = (const float*)d_in[7];
  const float* bc = (const float*)d_in[8];
  const float* n_rel_w = (const float*)d_in[9];
  const float* n_rel_b = (const float*)d_in[10];
  const float* n_root_w = (const float*)d_in[11];
  const float* c_rel_w = (const float*)d_in[12];
  const float* c_rel_b = (const float*)d_in[13];
  const float* c_root_w = (const float*)d_in[14];
  float* out = (float*)d_out;
  int* wsi = (int*)d_ws;
  float* wsf = (float*)d_ws;

  float* ab = wsf + OFF_AB;
  const unsigned short* xcb_s = (const unsigned short*)(wsi + OFF_XCB);
  const unsigned short* xnb_s = (const unsigned short*)(wsi + OFF_XNB);
  const int2* ent_n = (const int2*)(wsi + OFF_ENT_N);
  const int2* ent_c = (const int2*)(wsi + OFF_ENT_C);
  unsigned short* aggb = (unsigned short*)(wsi + OFF_AGGB);

  hipMemsetAsync(d_ws, 0, (size_t)WS_ZERO_N * sizeof(int), stream);

  pre_k<<<1152, 256, 0, stream>>>(vf, cf, (const int4*)es, (const int4*)ed, wsi);
  fin_scan_k<<<1, 256, 0, stream>>>(wsi, gn, bn, gc, bc);
  mid_k<<<2 * NCHUNK + 2344, 256, 0, stream>>>((const int4*)es, (const int4*)ed,
                                               (const float4*)ea, (const float4*)vf,
                                               (const float4*)cf, wsi);
  sort_k<<<NBK_T, 256, 0, stream>>>(wsi);

  gather_k<<<37500, 256, 0, stream>>>(xcb_s, xnb_s, ent_n, ent_c,
                                      wsi + OFF_OFF_N, wsi + OFF_OFF_C, aggb);

  out_k<<<960, 256, 0, stream>>>(aggb, xnb_s, xcb_s, vf, cf, ab,
                                 n_rel_w, n_rel_b, n_root_w,
                                 c_rel_w, c_rel_b, c_root_w, out);
}